// Round 1
// baseline (1137.148 us; speedup 1.0000x reference)
//
#include <hip/hip_runtime.h>

constexpr int NN = 50000;
constexpr int NREL = 3;
constexpr int NE = 400000;

// --- degree accumulation (HW fp32 atomics) ---
__global__ void degree_kernel(const int* __restrict__ edges,
                              float* __restrict__ inv_out,
                              float* __restrict__ inv_in) {
  int gid = blockIdx.x * blockDim.x + threadIdx.x;
  if (gid >= NREL * NE) return;
  int r = gid / NE;
  int e = gid - r * NE;
  const int* b = edges + (size_t)r * 2 * NE;
  int s = b[e];
  int d = b[NE + e];
  unsafeAtomicAdd(inv_out + r * NN + s, 1.0f);
  unsafeAtomicAdd(inv_in + r * NN + d, 1.0f);
}

__global__ void rsqrt_kernel(float* __restrict__ p, int n) {
  int gid = blockIdx.x * blockDim.x + threadIdx.x;
  if (gid < n) p[gid] = rsqrtf(fmaxf(p[gid], 1.0f));
}

// out[i][f] = sum_r b[r][f]  (full init of accumulator incl. bias)
template <int F>
__global__ void init_bias_kernel(float* __restrict__ out, const float* __restrict__ b) {
  int gid = blockIdx.x * blockDim.x + threadIdx.x;
  if (gid >= NN * F) return;
  int f = gid & (F - 1);
  out[gid] = b[f] + b[F + f] + b[2 * F + f];
}

__global__ void relu_kernel(float* __restrict__ p, int n) {
  int gid = blockIdx.x * blockDim.x + threadIdx.x;
  if (gid < n) p[gid] = fmaxf(p[gid], 0.0f);
}

// C[M][N] = (A[M][128] * rowscale[M]) @ W[128][N]; block tile 64x64, K=128 fully staged.
__global__ __launch_bounds__(256) void gemm_rowscale_kernel(
    const float* __restrict__ A, const float* __restrict__ W,
    const float* __restrict__ scale, float* __restrict__ C,
    int M, int N) {
  __shared__ float As[64][128];  // 32 KB
  __shared__ float Bs[128][64];  // 32 KB
  int t = threadIdx.x;
  int row0 = blockIdx.x * 64;
  int col0 = blockIdx.y * 64;
#pragma unroll
  for (int i = 0; i < 8; ++i) {
    int idx = t + i * 256;          // 0..2047 float4 slots of A tile
    int r = idx >> 5;
    int c4 = (idx & 31) << 2;
    int grow = row0 + r;
    float4 v = make_float4(0.f, 0.f, 0.f, 0.f);
    if (grow < M) {
      v = *(const float4*)(A + (size_t)grow * 128 + c4);
      float s = scale[grow];
      v.x *= s; v.y *= s; v.z *= s; v.w *= s;
    }
    *(float4*)(&As[r][c4]) = v;
  }
#pragma unroll
  for (int i = 0; i < 8; ++i) {
    int idx = t + i * 256;          // 0..2047 float4 slots of B tile
    int k = idx >> 4;
    int c4 = (idx & 15) << 2;
    *(float4*)(&Bs[k][c4]) = *(const float4*)(W + (size_t)k * N + col0 + c4);
  }
  __syncthreads();
  int tx4 = (t & 15) << 2;
  int ty4 = (t >> 4) << 2;
  float acc[4][4] = {};
#pragma unroll 8
  for (int k = 0; k < 128; k += 4) {
    float4 b0 = *(const float4*)(&Bs[k + 0][tx4]);
    float4 b1 = *(const float4*)(&Bs[k + 1][tx4]);
    float4 b2 = *(const float4*)(&Bs[k + 2][tx4]);
    float4 b3 = *(const float4*)(&Bs[k + 3][tx4]);
#pragma unroll
    for (int m = 0; m < 4; ++m) {
      float4 a = *(const float4*)(&As[ty4 + m][k]);
      acc[m][0] += a.x * b0.x + a.y * b1.x + a.z * b2.x + a.w * b3.x;
      acc[m][1] += a.x * b0.y + a.y * b1.y + a.z * b2.y + a.w * b3.y;
      acc[m][2] += a.x * b0.z + a.y * b1.z + a.z * b2.z + a.w * b3.z;
      acc[m][3] += a.x * b0.w + a.y * b1.w + a.z * b2.w + a.w * b3.w;
    }
  }
#pragma unroll
  for (int m = 0; m < 4; ++m) {
    int row = row0 + ty4 + m;
    if (row < M) {
      float4 v = make_float4(acc[m][0], acc[m][1], acc[m][2], acc[m][3]);
      *(float4*)(C + (size_t)row * N + col0 + tx4) = v;
    }
  }
}

// per (edge, feature) thread: acc[dst][f] += hproj[src][f] * inv_in[dst]
template <int LOGF>
__global__ void scatter_kernel(const float* __restrict__ hp,
                               const int* __restrict__ src,
                               const int* __restrict__ dst,
                               const float* __restrict__ inv_in_r,
                               float* __restrict__ acc) {
  int gid = blockIdx.x * blockDim.x + threadIdx.x;
  constexpr int F = 1 << LOGF;
  if (gid >= NE * F) return;
  int e = gid >> LOGF;
  int f = gid & (F - 1);
  int s = src[e];
  int d = dst[e];
  float v = hp[(s << LOGF) + f] * inv_in_r[d];
  unsafeAtomicAdd(acc + (d << LOGF) + f, v);
}

extern "C" void kernel_launch(void* const* d_in, const int* in_sizes, int n_in,
                              void* d_out, int out_size, void* d_ws, size_t ws_size,
                              hipStream_t stream) {
  const float* x   = (const float*)d_in[0];
  const int* edges = (const int*)d_in[1];
  const float* W1  = (const float*)d_in[2];
  const float* b1  = (const float*)d_in[3];
  const float* W2  = (const float*)d_in[4];
  const float* b2  = (const float*)d_in[5];
  float* out = (float*)d_out;
  float* ws  = (float*)d_ws;

  float* inv_out = ws;                       // [3][NN]
  float* inv_in  = ws + NREL * NN;           // [3][NN]
  float* h = ws + 2 * NREL * NN;             // [NN][128] accumulator / layer-2 input
  float* p = h + (size_t)NN * 128;           // [NN][128] projection scratch

  // degrees -> rsqrt (shared by both layers)
  hipMemsetAsync(ws, 0, (size_t)2 * NREL * NN * sizeof(float), stream);
  degree_kernel<<<(NREL * NE + 255) / 256, 256, 0, stream>>>(edges, inv_out, inv_in);
  rsqrt_kernel<<<(2 * NREL * NN + 255) / 256, 256, 0, stream>>>(ws, 2 * NREL * NN);

  // ---- layer 1: h = relu(sum_r scatter(gemm(x*so_r, W1_r)) * si_r + sum_r b1_r)
  init_bias_kernel<128><<<(NN * 128 + 255) / 256, 256, 0, stream>>>(h, b1);
  dim3 g1((NN + 63) / 64, 2);
  for (int r = 0; r < NREL; ++r) {
    gemm_rowscale_kernel<<<g1, 256, 0, stream>>>(
        x, W1 + (size_t)r * 128 * 128, inv_out + r * NN, p, NN, 128);
    scatter_kernel<7><<<(NE * 128) / 256, 256, 0, stream>>>(
        p, edges + (size_t)r * 2 * NE, edges + (size_t)r * 2 * NE + NE,
        inv_in + r * NN, h);
  }
  relu_kernel<<<(NN * 128 + 255) / 256, 256, 0, stream>>>(h, NN * 128);

  // ---- layer 2: out = sum_r scatter(gemm(h*so_r, W2_r)) * si_r + sum_r b2_r
  init_bias_kernel<64><<<(NN * 64 + 255) / 256, 256, 0, stream>>>(out, b2);
  dim3 g2((NN + 63) / 64, 1);
  for (int r = 0; r < NREL; ++r) {
    gemm_rowscale_kernel<<<g2, 256, 0, stream>>>(
        h, W2 + (size_t)r * 128 * 64, inv_out + r * NN, p, NN, 64);
    scatter_kernel<6><<<(NE * 64 + 255) / 256, 256, 0, stream>>>(
        p, edges + (size_t)r * 2 * NE, edges + (size_t)r * 2 * NE + NE,
        inv_in + r * NN, out);
  }
}

// Round 2
// 780.303 us; speedup vs baseline: 1.4573x; 1.4573x over previous
//
#include <hip/hip_runtime.h>

constexpr int NN = 50000;
constexpr int NREL = 3;
constexpr int NE = 400000;

// --- integer degree histogram ---
__global__ void degree_kernel(const int* __restrict__ edges,
                              int* __restrict__ cnt_out,
                              int* __restrict__ cnt_in) {
  int gid = blockIdx.x * blockDim.x + threadIdx.x;
  if (gid >= NREL * NE) return;
  int r = gid / NE;
  int e = gid - r * NE;
  const int* b = edges + (size_t)r * 2 * NE;
  atomicAdd(cnt_out + r * NN + b[e], 1);
  atomicAdd(cnt_in + r * NN + b[NE + e], 1);
}

// o[i] = rsqrt(max(cnt[i],1))  — covers so (from cnt_out) and si (from cnt_in) in one call
__global__ void rsqrt_counts_kernel(const int* __restrict__ cnt, float* __restrict__ o, int n) {
  int gid = blockIdx.x * blockDim.x + threadIdx.x;
  if (gid < n) o[gid] = rsqrtf((float)max(cnt[gid], 1));
}

// exclusive scan of cnt_in per relation -> rowptr (one block per relation)
__global__ __launch_bounds__(1024) void scan_kernel(const int* __restrict__ cnt,
                                                    int* __restrict__ rowptr) {
  int r = blockIdx.x;
  const int* c = cnt + r * NN;
  int* rp = rowptr + r * (NN + 1);
  __shared__ int tmp[1024];
  __shared__ int carry;
  if (threadIdx.x == 0) { carry = 0; rp[0] = 0; }
  __syncthreads();
  for (int base = 0; base < NN; base += 1024) {
    int i = base + threadIdx.x;
    int v = (i < NN) ? c[i] : 0;
    tmp[threadIdx.x] = v;
    __syncthreads();
    for (int off = 1; off < 1024; off <<= 1) {
      int t = (threadIdx.x >= off) ? tmp[threadIdx.x - off] : 0;
      __syncthreads();
      tmp[threadIdx.x] += t;
      __syncthreads();
    }
    if (i < NN) rp[i + 1] = carry + tmp[threadIdx.x];
    __syncthreads();
    if (threadIdx.x == 0) carry += tmp[1023];
    __syncthreads();
  }
}

// scatter src ids into dst-sorted CSR
__global__ void fill_kernel(const int* __restrict__ edges,
                            const int* __restrict__ rowptr,
                            int* __restrict__ cursor,
                            int* __restrict__ csr_src) {
  int gid = blockIdx.x * blockDim.x + threadIdx.x;
  if (gid >= NREL * NE) return;
  int r = gid / NE;
  int e = gid - r * NE;
  const int* b = edges + (size_t)r * 2 * NE;
  int s = b[e];
  int d = b[NE + e];
  int pos = atomicAdd(cursor + r * NN + d, 1);
  csr_src[(size_t)r * NE + rowptr[r * (NN + 1) + d] + pos] = s;
}

// out[i][f] = sum_r b[r][f]
template <int F>
__global__ void init_bias_kernel(float* __restrict__ out, const float* __restrict__ b) {
  int gid = blockIdx.x * blockDim.x + threadIdx.x;
  if (gid >= NN * F) return;
  int f = gid & (F - 1);
  out[gid] = b[f] + b[F + f] + b[2 * F + f];
}

// layer-1 aggregate: agg[d][:] = si[d] * sum_{s in row(d)} x[s][:] * so[s]   (F=128, wave/row)
__global__ __launch_bounds__(256) void agg_l1_kernel(
    const float* __restrict__ x, const int* __restrict__ csr,
    const int* __restrict__ rowptr, const float* __restrict__ so,
    const float* __restrict__ si, float* __restrict__ agg) {
  int w = (blockIdx.x * blockDim.x + threadIdx.x) >> 6;
  int lane = threadIdx.x & 63;
  if (w >= NN) return;
  int beg = rowptr[w], end = rowptr[w + 1];
  float ax = 0.f, ay = 0.f;
  for (int e = beg; e < end; ++e) {
    int s = csr[e];
    float wgt = so[s];
    float2 v = *(const float2*)(x + (size_t)s * 128 + lane * 2);
    ax += v.x * wgt;
    ay += v.y * wgt;
  }
  float sd = si[w];
  float2 o;
  o.x = ax * sd;
  o.y = ay * sd;
  *(float2*)(agg + (size_t)w * 128 + lane * 2) = o;
}

// layer-2 aggregate: out[d][:] += si[d] * sum_{s in row(d)} proj[s][:]   (F=64, wave/row)
__global__ __launch_bounds__(256) void agg_l2_kernel(
    const float* __restrict__ proj, const int* __restrict__ csr,
    const int* __restrict__ rowptr, const float* __restrict__ si,
    float* __restrict__ out) {
  int w = (blockIdx.x * blockDim.x + threadIdx.x) >> 6;
  int lane = threadIdx.x & 63;
  if (w >= NN) return;
  int beg = rowptr[w], end = rowptr[w + 1];
  float a = 0.f;
  for (int e = beg; e < end; ++e) {
    int s = csr[e];
    a += proj[(size_t)s * 64 + lane];
  }
  out[(size_t)w * 64 + lane] += a * si[w];
}

// C[M][N] (+)= (A[M][128] * rowscale?) @ W[128][N]; 64x64 tile, K=128 fully staged.
template <bool SCALE, bool ACCUM, bool RELU>
__global__ __launch_bounds__(256) void gemm_kernel(
    const float* __restrict__ A, const float* __restrict__ W,
    const float* __restrict__ scale, float* __restrict__ C,
    int M, int N) {
  __shared__ float As[64][128];
  __shared__ float Bs[128][64];
  int t = threadIdx.x;
  int row0 = blockIdx.x * 64;
  int col0 = blockIdx.y * 64;
#pragma unroll
  for (int i = 0; i < 8; ++i) {
    int idx = t + i * 256;
    int r = idx >> 5;
    int c4 = (idx & 31) << 2;
    int grow = row0 + r;
    float4 v = make_float4(0.f, 0.f, 0.f, 0.f);
    if (grow < M) {
      v = *(const float4*)(A + (size_t)grow * 128 + c4);
      if (SCALE) {
        float s = scale[grow];
        v.x *= s; v.y *= s; v.z *= s; v.w *= s;
      }
    }
    *(float4*)(&As[r][c4]) = v;
  }
#pragma unroll
  for (int i = 0; i < 8; ++i) {
    int idx = t + i * 256;
    int k = idx >> 4;
    int c4 = (idx & 15) << 2;
    *(float4*)(&Bs[k][c4]) = *(const float4*)(W + (size_t)k * N + col0 + c4);
  }
  __syncthreads();
  int tx4 = (t & 15) << 2;
  int ty4 = (t >> 4) << 2;
  float acc[4][4] = {};
#pragma unroll 8
  for (int k = 0; k < 128; k += 4) {
    float4 b0 = *(const float4*)(&Bs[k + 0][tx4]);
    float4 b1 = *(const float4*)(&Bs[k + 1][tx4]);
    float4 b2 = *(const float4*)(&Bs[k + 2][tx4]);
    float4 b3 = *(const float4*)(&Bs[k + 3][tx4]);
#pragma unroll
    for (int m = 0; m < 4; ++m) {
      float4 a = *(const float4*)(&As[ty4 + m][k]);
      acc[m][0] += a.x * b0.x + a.y * b1.x + a.z * b2.x + a.w * b3.x;
      acc[m][1] += a.x * b0.y + a.y * b1.y + a.z * b2.y + a.w * b3.y;
      acc[m][2] += a.x * b0.z + a.y * b1.z + a.z * b2.z + a.w * b3.z;
      acc[m][3] += a.x * b0.w + a.y * b1.w + a.z * b2.w + a.w * b3.w;
    }
  }
#pragma unroll
  for (int m = 0; m < 4; ++m) {
    int row = row0 + ty4 + m;
    if (row < M) {
      float* cp = C + (size_t)row * N + col0 + tx4;
      float4 v = make_float4(acc[m][0], acc[m][1], acc[m][2], acc[m][3]);
      if (ACCUM) {
        float4 old = *(const float4*)cp;
        v.x += old.x; v.y += old.y; v.z += old.z; v.w += old.w;
      }
      if (RELU) {
        v.x = fmaxf(v.x, 0.f); v.y = fmaxf(v.y, 0.f);
        v.z = fmaxf(v.z, 0.f); v.w = fmaxf(v.w, 0.f);
      }
      *(float4*)cp = v;
    }
  }
}

extern "C" void kernel_launch(void* const* d_in, const int* in_sizes, int n_in,
                              void* d_out, int out_size, void* d_ws, size_t ws_size,
                              hipStream_t stream) {
  const float* x   = (const float*)d_in[0];
  const int* edges = (const int*)d_in[1];
  const float* W1  = (const float*)d_in[2];
  const float* b1  = (const float*)d_in[3];
  const float* W2  = (const float*)d_in[4];
  const float* b2  = (const float*)d_in[5];
  float* out = (float*)d_out;

  // workspace layout (ints then floats), ~59.4 MB total
  int* cnt_out = (int*)d_ws;                     // [3*NN]
  int* cnt_in  = cnt_out + NREL * NN;            // [3*NN]
  int* rowptr  = cnt_in + NREL * NN;             // [3*(NN+1)]
  int* cursor  = rowptr + NREL * (NN + 1);       // [3*NN]
  int* csr_src = cursor + NREL * NN;             // [3*NE]
  float* so    = (float*)(csr_src + NREL * NE);  // [3*NN]
  float* si    = so + NREL * NN;                 // [3*NN]
  float* region = si + NREL * NN;                // [NN*128] agg / proj scratch
  float* h      = region + (size_t)NN * 128;     // [NN*128]

  // --- CSR build + norms (shared by both layers) ---
  hipMemsetAsync(cnt_out, 0, (size_t)2 * NREL * NN * sizeof(int), stream);
  degree_kernel<<<(NREL * NE + 255) / 256, 256, 0, stream>>>(edges, cnt_out, cnt_in);
  // so,si contiguous; cnt_out,cnt_in contiguous -> single call
  rsqrt_counts_kernel<<<(2 * NREL * NN + 255) / 256, 256, 0, stream>>>(cnt_out, so, 2 * NREL * NN);
  scan_kernel<<<NREL, 1024, 0, stream>>>(cnt_in, rowptr);
  hipMemsetAsync(cursor, 0, (size_t)NREL * NN * sizeof(int), stream);
  fill_kernel<<<(NREL * NE + 255) / 256, 256, 0, stream>>>(edges, rowptr, cursor, csr_src);

  const int aggBlocks = (NN * 64 + 255) / 256;  // one wave per dst row

  // ---- layer 1: aggregate-first, GEMM accumulates into h, ReLU fused into last GEMM
  init_bias_kernel<128><<<(NN * 128 + 255) / 256, 256, 0, stream>>>(h, b1);
  dim3 g1((NN + 63) / 64, 2);
  for (int r = 0; r < NREL; ++r) {
    agg_l1_kernel<<<aggBlocks, 256, 0, stream>>>(
        x, csr_src + (size_t)r * NE, rowptr + r * (NN + 1), so + r * NN, si + r * NN, region);
    if (r < NREL - 1)
      gemm_kernel<false, true, false><<<g1, 256, 0, stream>>>(
          region, W1 + (size_t)r * 128 * 128, nullptr, h, NN, 128);
    else
      gemm_kernel<false, true, true><<<g1, 256, 0, stream>>>(
          region, W1 + (size_t)r * 128 * 128, nullptr, h, NN, 128);
  }

  // ---- layer 2: project-first (64-d), CSR gather-sum into out
  init_bias_kernel<64><<<(NN * 64 + 255) / 256, 256, 0, stream>>>(out, b2);
  dim3 g2((NN + 63) / 64, 1);
  for (int r = 0; r < NREL; ++r) {
    gemm_kernel<true, false, false><<<g2, 256, 0, stream>>>(
        h, W2 + (size_t)r * 128 * 64, so + r * NN, region, NN, 64);
    agg_l2_kernel<<<aggBlocks, 256, 0, stream>>>(
        region, csr_src + (size_t)r * NE, rowptr + r * (NN + 1), si + r * NN, out);
  }
}

// Round 3
// 499.598 us; speedup vs baseline: 2.2761x; 1.5619x over previous
//
#include <hip/hip_runtime.h>

constexpr int NN = 50000;
constexpr int NREL = 3;
constexpr int NE = 400000;
constexpr int CAP = 24;        // ELL capacity; Poisson(8) tail at 24 ~ 4e-9/node
constexpr int MAXSPILL = 4096; // guaranteed-correctness overflow path

// --- fused degree histogram + ELL fill (dst-sorted adjacency, ushort src ids) ---
__global__ void ell_build_kernel(const int* __restrict__ edges,
                                 int* __restrict__ cnt_out,
                                 int* __restrict__ cnt_in,
                                 unsigned short* __restrict__ ell,
                                 int* __restrict__ nspill,
                                 int* __restrict__ spill) {
  int gid = blockIdx.x * blockDim.x + threadIdx.x;
  if (gid >= NREL * NE) return;
  int r = gid / NE;
  int e = gid - r * NE;
  const int* b = edges + (size_t)r * 2 * NE;
  int s = b[e];
  int d = b[NE + e];
  atomicAdd(cnt_out + r * NN + s, 1);
  int pos = atomicAdd(cnt_in + r * NN + d, 1);
  if (pos < CAP) {
    ell[((size_t)r * NN + d) * CAP + pos] = (unsigned short)s;
  } else {
    int i = atomicAdd(nspill, 1);
    if (i < MAXSPILL) { spill[3 * i] = r; spill[3 * i + 1] = d; spill[3 * i + 2] = s; }
  }
}

// layer-1 aggregate: region[d][:] = si[d] * sum_{s in row(d)} x[s][:] * so[s]
// one 32-lane half-wave per row; float4/lane; 2-edge unroll.
// cnt_in/cnt_out/ell pre-offset to relation r by caller.
__global__ __launch_bounds__(256) void agg_l1_kernel(
    const float* __restrict__ x, const unsigned short* __restrict__ ell,
    const int* __restrict__ cnt_in, const int* __restrict__ cnt_out,
    const int* __restrict__ nspill, const int* __restrict__ spill,
    int r, float* __restrict__ region) {
  int row = (blockIdx.x * blockDim.x + threadIdx.x) >> 5;
  if (row >= NN) return;
  int lane = threadIdx.x & 31;
  int deg = cnt_in[row];
  int n = min(deg, CAP);
  const unsigned short* er = ell + (size_t)row * CAP;
  float4 a0 = make_float4(0.f, 0.f, 0.f, 0.f);
  float4 a1 = make_float4(0.f, 0.f, 0.f, 0.f);
  int e = 0;
  for (; e + 1 < n; e += 2) {
    int s0 = er[e], s1 = er[e + 1];
    float w0 = rsqrtf((float)max(cnt_out[s0], 1));
    float w1 = rsqrtf((float)max(cnt_out[s1], 1));
    float4 v0 = *(const float4*)(x + (size_t)s0 * 128 + lane * 4);
    float4 v1 = *(const float4*)(x + (size_t)s1 * 128 + lane * 4);
    a0.x += w0 * v0.x; a0.y += w0 * v0.y; a0.z += w0 * v0.z; a0.w += w0 * v0.w;
    a1.x += w1 * v1.x; a1.y += w1 * v1.y; a1.z += w1 * v1.z; a1.w += w1 * v1.w;
  }
  if (e < n) {
    int s0 = er[e];
    float w0 = rsqrtf((float)max(cnt_out[s0], 1));
    float4 v0 = *(const float4*)(x + (size_t)s0 * 128 + lane * 4);
    a0.x += w0 * v0.x; a0.y += w0 * v0.y; a0.z += w0 * v0.z; a0.w += w0 * v0.w;
  }
  int ns = *nspill;
  for (int i = 0; i < ns; ++i) {
    if (spill[3 * i] == r && spill[3 * i + 1] == row) {
      int s0 = spill[3 * i + 2];
      float w0 = rsqrtf((float)max(cnt_out[s0], 1));
      float4 v0 = *(const float4*)(x + (size_t)s0 * 128 + lane * 4);
      a0.x += w0 * v0.x; a0.y += w0 * v0.y; a0.z += w0 * v0.z; a0.w += w0 * v0.w;
    }
  }
  float si = rsqrtf((float)max(deg, 1));
  float4 o;
  o.x = (a0.x + a1.x) * si; o.y = (a0.y + a1.y) * si;
  o.z = (a0.z + a1.z) * si; o.w = (a0.w + a1.w) * si;
  *(float4*)(region + (size_t)row * 128 + lane * 4) = o;
}

// layer-2 aggregate: out[d][:] (=|+=) si[d] * sum_{s in row(d)} proj[s][:] (+ bias on INIT)
// one 16-lane quarter-wave per row; float4/lane.
template <bool INIT>
__global__ __launch_bounds__(256) void agg_l2_kernel(
    const float* __restrict__ proj, const unsigned short* __restrict__ ell,
    const int* __restrict__ cnt_in,
    const int* __restrict__ nspill, const int* __restrict__ spill,
    int r, const float* __restrict__ b2, float* __restrict__ out) {
  int row = (blockIdx.x * blockDim.x + threadIdx.x) >> 4;
  if (row >= NN) return;
  int lane = threadIdx.x & 15;
  int deg = cnt_in[row];
  int n = min(deg, CAP);
  const unsigned short* er = ell + (size_t)row * CAP;
  float4 a0 = make_float4(0.f, 0.f, 0.f, 0.f);
  float4 a1 = make_float4(0.f, 0.f, 0.f, 0.f);
  int e = 0;
  for (; e + 1 < n; e += 2) {
    int s0 = er[e], s1 = er[e + 1];
    float4 v0 = *(const float4*)(proj + (size_t)s0 * 64 + lane * 4);
    float4 v1 = *(const float4*)(proj + (size_t)s1 * 64 + lane * 4);
    a0.x += v0.x; a0.y += v0.y; a0.z += v0.z; a0.w += v0.w;
    a1.x += v1.x; a1.y += v1.y; a1.z += v1.z; a1.w += v1.w;
  }
  if (e < n) {
    int s0 = er[e];
    float4 v0 = *(const float4*)(proj + (size_t)s0 * 64 + lane * 4);
    a0.x += v0.x; a0.y += v0.y; a0.z += v0.z; a0.w += v0.w;
  }
  int ns = *nspill;
  for (int i = 0; i < ns; ++i) {
    if (spill[3 * i] == r && spill[3 * i + 1] == row) {
      int s0 = spill[3 * i + 2];
      float4 v0 = *(const float4*)(proj + (size_t)s0 * 64 + lane * 4);
      a0.x += v0.x; a0.y += v0.y; a0.z += v0.z; a0.w += v0.w;
    }
  }
  float si = rsqrtf((float)max(deg, 1));
  float4 res;
  res.x = (a0.x + a1.x) * si; res.y = (a0.y + a1.y) * si;
  res.z = (a0.z + a1.z) * si; res.w = (a0.w + a1.w) * si;
  float* op = out + (size_t)row * 64 + lane * 4;
  if (INIT) {
    int f = lane * 4;
    res.x += b2[f + 0] + b2[64 + f + 0] + b2[128 + f + 0];
    res.y += b2[f + 1] + b2[64 + f + 1] + b2[128 + f + 1];
    res.z += b2[f + 2] + b2[64 + f + 2] + b2[128 + f + 2];
    res.w += b2[f + 3] + b2[64 + f + 3] + b2[128 + f + 3];
    *(float4*)op = res;
  } else {
    float4 old = *(const float4*)op;
    res.x += old.x; res.y += old.y; res.z += old.z; res.w += old.w;
    *(float4*)op = res;
  }
}

// C[M][N] (+)= (A[M][128] * rsqrt(cnt)?) @ W[128][N] (+ sum-of-3 bias) (relu?)
template <bool SCALE, bool ACCUM, bool RELU, bool BIAS>
__global__ __launch_bounds__(256) void gemm_kernel(
    const float* __restrict__ A, const float* __restrict__ W,
    const int* __restrict__ cnt_scale, const float* __restrict__ bias3,
    float* __restrict__ C, int M, int N) {
  __shared__ float As[64][128];
  __shared__ float Bs[128][64];
  int t = threadIdx.x;
  int row0 = blockIdx.x * 64;
  int col0 = blockIdx.y * 64;
#pragma unroll
  for (int i = 0; i < 8; ++i) {
    int idx = t + i * 256;
    int r = idx >> 5;
    int c4 = (idx & 31) << 2;
    int grow = row0 + r;
    float4 v = make_float4(0.f, 0.f, 0.f, 0.f);
    if (grow < M) {
      v = *(const float4*)(A + (size_t)grow * 128 + c4);
      if (SCALE) {
        float s = rsqrtf((float)max(cnt_scale[grow], 1));
        v.x *= s; v.y *= s; v.z *= s; v.w *= s;
      }
    }
    *(float4*)(&As[r][c4]) = v;
  }
#pragma unroll
  for (int i = 0; i < 8; ++i) {
    int idx = t + i * 256;
    int k = idx >> 4;
    int c4 = (idx & 15) << 2;
    *(float4*)(&Bs[k][c4]) = *(const float4*)(W + (size_t)k * N + col0 + c4);
  }
  __syncthreads();
  int tx4 = (t & 15) << 2;
  int ty4 = (t >> 4) << 2;
  float acc[4][4] = {};
#pragma unroll 8
  for (int k = 0; k < 128; k += 4) {
    float4 b0 = *(const float4*)(&Bs[k + 0][tx4]);
    float4 b1 = *(const float4*)(&Bs[k + 1][tx4]);
    float4 b2 = *(const float4*)(&Bs[k + 2][tx4]);
    float4 b3 = *(const float4*)(&Bs[k + 3][tx4]);
#pragma unroll
    for (int m = 0; m < 4; ++m) {
      float4 a = *(const float4*)(&As[ty4 + m][k]);
      acc[m][0] += a.x * b0.x + a.y * b1.x + a.z * b2.x + a.w * b3.x;
      acc[m][1] += a.x * b0.y + a.y * b1.y + a.z * b2.y + a.w * b3.y;
      acc[m][2] += a.x * b0.z + a.y * b1.z + a.z * b2.z + a.w * b3.z;
      acc[m][3] += a.x * b0.w + a.y * b1.w + a.z * b2.w + a.w * b3.w;
    }
  }
#pragma unroll
  for (int m = 0; m < 4; ++m) {
    int row = row0 + ty4 + m;
    if (row < M) {
      float* cp = C + (size_t)row * N + col0 + tx4;
      float4 v = make_float4(acc[m][0], acc[m][1], acc[m][2], acc[m][3]);
      if (BIAS) {
        int col = col0 + tx4;
        v.x += bias3[col + 0] + bias3[N + col + 0] + bias3[2 * N + col + 0];
        v.y += bias3[col + 1] + bias3[N + col + 1] + bias3[2 * N + col + 1];
        v.z += bias3[col + 2] + bias3[N + col + 2] + bias3[2 * N + col + 2];
        v.w += bias3[col + 3] + bias3[N + col + 3] + bias3[2 * N + col + 3];
      }
      if (ACCUM) {
        float4 old = *(const float4*)cp;
        v.x += old.x; v.y += old.y; v.z += old.z; v.w += old.w;
      }
      if (RELU) {
        v.x = fmaxf(v.x, 0.f); v.y = fmaxf(v.y, 0.f);
        v.z = fmaxf(v.z, 0.f); v.w = fmaxf(v.w, 0.f);
      }
      *(float4*)cp = v;
    }
  }
}

extern "C" void kernel_launch(void* const* d_in, const int* in_sizes, int n_in,
                              void* d_out, int out_size, void* d_ws, size_t ws_size,
                              hipStream_t stream) {
  const float* x   = (const float*)d_in[0];
  const int* edges = (const int*)d_in[1];
  const float* W1  = (const float*)d_in[2];
  const float* b1  = (const float*)d_in[3];
  const float* W2  = (const float*)d_in[4];
  const float* b2  = (const float*)d_in[5];
  float* out = (float*)d_out;

  // workspace layout (~56.9 MiB)
  int* cnt_out = (int*)d_ws;                         // [3*NN]
  int* cnt_in  = cnt_out + NREL * NN;                // [3*NN]
  int* nspill  = cnt_in + NREL * NN;                 // [4] (1 used)
  int* spill   = nspill + 4;                         // [3*MAXSPILL]
  unsigned short* ell = (unsigned short*)(spill + 3 * MAXSPILL);  // [3*NN*CAP]
  float* region = (float*)(ell + (size_t)NREL * NN * CAP);        // [NN*128]
  float* h      = region + (size_t)NN * 128;                      // [NN*128]

  // zero counters + spill count, build ELL (shared by both layers)
  hipMemsetAsync(d_ws, 0, (size_t)(2 * NREL * NN + 4) * sizeof(int), stream);
  ell_build_kernel<<<(NREL * NE + 255) / 256, 256, 0, stream>>>(
      edges, cnt_out, cnt_in, ell, nspill, spill);

  // ---- layer 1: aggregate-first; GEMMs accumulate into h; bias in r=0, ReLU in r=2
  dim3 g1((NN + 63) / 64, 2);
  for (int r = 0; r < NREL; ++r) {
    agg_l1_kernel<<<(NN * 32 + 255) / 256, 256, 0, stream>>>(
        x, ell + (size_t)r * NN * CAP, cnt_in + r * NN, cnt_out + r * NN,
        nspill, spill, r, region);
    const float* Wr = W1 + (size_t)r * 128 * 128;
    if (r == 0)
      gemm_kernel<false, false, false, true><<<g1, 256, 0, stream>>>(
          region, Wr, nullptr, b1, h, NN, 128);
    else if (r == 1)
      gemm_kernel<false, true, false, false><<<g1, 256, 0, stream>>>(
          region, Wr, nullptr, nullptr, h, NN, 128);
    else
      gemm_kernel<false, true, true, false><<<g1, 256, 0, stream>>>(
          region, Wr, nullptr, nullptr, h, NN, 128);
  }

  // ---- layer 2: project-first (64-d); agg r=0 initializes out with bias
  dim3 g2((NN + 63) / 64, 1);
  for (int r = 0; r < NREL; ++r) {
    gemm_kernel<true, false, false, false><<<g2, 256, 0, stream>>>(
        h, W2 + (size_t)r * 128 * 64, cnt_out + r * NN, nullptr, region, NN, 64);
    if (r == 0)
      agg_l2_kernel<true><<<(NN * 16 + 255) / 256, 256, 0, stream>>>(
          region, ell + (size_t)r * NN * CAP, cnt_in + r * NN,
          nspill, spill, r, b2, out);
    else
      agg_l2_kernel<false><<<(NN * 16 + 255) / 256, 256, 0, stream>>>(
          region, ell + (size_t)r * NN * CAP, cnt_in + r * NN,
          nspill, spill, r, b2, out);
  }
}

// Round 4
// 454.542 us; speedup vs baseline: 2.5017x; 1.0991x over previous
//
#include <hip/hip_runtime.h>

constexpr int NN = 50000;
constexpr int NREL = 3;
constexpr int NE = 400000;
constexpr int CAP = 24;        // ELL capacity; Poisson(8) tail at 24 ~ 4e-9/node
constexpr int MAXSPILL = 4096;

constexpr int BB = (NREL * NE + 255) / 256;   // 4688 build blocks
constexpr int G1X = (NN + 63) / 64;           // 782 gemm row-blocks
constexpr int GEMM1_BLKS = G1X * 2 * NREL;    // 4692 L1 gemm blocks

// ---- plain GEMM tile body: C[M][N] = (A * rsqrt(cnt)?) @ W, 64x64 tile, K=128 ----
template <bool SCALE>
__device__ __forceinline__ void gemm_body(
    const float* __restrict__ A, const float* __restrict__ W,
    const int* __restrict__ cnt_scale, float* __restrict__ C,
    int M, int N, int row0, int col0) {
  __shared__ float As[64][128];
  __shared__ float Bs[128][64];
  int t = threadIdx.x;
#pragma unroll
  for (int i = 0; i < 8; ++i) {
    int idx = t + i * 256;
    int r = idx >> 5;
    int c4 = (idx & 31) << 2;
    int grow = row0 + r;
    float4 v = make_float4(0.f, 0.f, 0.f, 0.f);
    if (grow < M) {
      v = *(const float4*)(A + (size_t)grow * 128 + c4);
      if (SCALE) {
        float s = rsqrtf((float)max(cnt_scale[grow], 1));
        v.x *= s; v.y *= s; v.z *= s; v.w *= s;
      }
    }
    *(float4*)(&As[r][c4]) = v;
  }
#pragma unroll
  for (int i = 0; i < 8; ++i) {
    int idx = t + i * 256;
    int k = idx >> 4;
    int c4 = (idx & 15) << 2;
    *(float4*)(&Bs[k][c4]) = *(const float4*)(W + (size_t)k * N + col0 + c4);
  }
  __syncthreads();
  int tx4 = (t & 15) << 2;
  int ty4 = (t >> 4) << 2;
  float acc[4][4] = {};
#pragma unroll 8
  for (int k = 0; k < 128; k += 4) {
    float4 b0 = *(const float4*)(&Bs[k + 0][tx4]);
    float4 b1 = *(const float4*)(&Bs[k + 1][tx4]);
    float4 b2 = *(const float4*)(&Bs[k + 2][tx4]);
    float4 b3 = *(const float4*)(&Bs[k + 3][tx4]);
#pragma unroll
    for (int m = 0; m < 4; ++m) {
      float4 a = *(const float4*)(&As[ty4 + m][k]);
      acc[m][0] += a.x * b0.x + a.y * b1.x + a.z * b2.x + a.w * b3.x;
      acc[m][1] += a.x * b0.y + a.y * b1.y + a.z * b2.y + a.w * b3.y;
      acc[m][2] += a.x * b0.z + a.y * b1.z + a.z * b2.z + a.w * b3.z;
      acc[m][3] += a.x * b0.w + a.y * b1.w + a.z * b2.w + a.w * b3.w;
    }
  }
#pragma unroll
  for (int m = 0; m < 4; ++m) {
    int row = row0 + ty4 + m;
    if (row < M)
      *(float4*)(C + (size_t)row * N + col0 + tx4) =
          make_float4(acc[m][0], acc[m][1], acc[m][2], acc[m][3]);
  }
}

// ---- fused: ELL build (blocks [0,BB)) + 3x L1 GEMM proj1_r = x@W1_r (blocks [BB,..)) ----
__global__ __launch_bounds__(256) void fused_build_gemm1_kernel(
    const int* __restrict__ edges, int* __restrict__ cnt_out, int* __restrict__ cnt_in,
    unsigned short* __restrict__ ell, int* __restrict__ nspill, int* __restrict__ spill,
    const float* __restrict__ x, const float* __restrict__ W1, float* __restrict__ proj1) {
  if (blockIdx.x < BB) {
    int gid = blockIdx.x * 256 + threadIdx.x;
    if (gid >= NREL * NE) return;
    int r = gid / NE;
    int e = gid - r * NE;
    const int* b = edges + (size_t)r * 2 * NE;
    int s = b[e];
    int d = b[NE + e];
    atomicAdd(cnt_out + r * NN + s, 1);
    int pos = atomicAdd(cnt_in + r * NN + d, 1);
    if (pos < CAP) {
      ell[((size_t)r * NN + d) * CAP + pos] = (unsigned short)s;
    } else {
      int i = atomicAdd(nspill, 1);
      if (i < MAXSPILL) { spill[3 * i] = r; spill[3 * i + 1] = d; spill[3 * i + 2] = s; }
    }
  } else {
    int g = blockIdx.x - BB;
    int r = g / (G1X * 2);
    int rem = g - r * (G1X * 2);
    int bx = rem >> 1, by = rem & 1;
    gemm_body<false>(x, W1 + (size_t)r * 128 * 128, nullptr,
                     proj1 + (size_t)r * NN * 128, NN, 128, bx * 64, by * 64);
  }
}

// standalone GEMMs (fallback path / layer 2)
__global__ __launch_bounds__(256) void gemm1_single_kernel(
    const float* __restrict__ x, const float* __restrict__ W1r, float* __restrict__ proj) {
  gemm_body<false>(x, W1r, nullptr, proj, NN, 128, blockIdx.x * 64, blockIdx.y * 64);
}
__global__ __launch_bounds__(256) void gemm2_kernel(
    const float* __restrict__ h, const float* __restrict__ W2,
    const int* __restrict__ cnt_out, float* __restrict__ proj2, int relStride) {
  int r = blockIdx.z;
  gemm_body<true>(h, W2 + (size_t)r * 128 * 64, cnt_out + r * NN,
                  proj2 + (size_t)r * relStride, NN, 64, blockIdx.x * 64, 0);
}

// ---- layer-1 aggregate, all 3 relations, bias+relu fused; half-wave (32 lanes) per row ----
__global__ __launch_bounds__(256) void agg1_all_kernel(
    const float* __restrict__ proj1, const unsigned short* __restrict__ ell,
    const int* __restrict__ cnt_in, const int* __restrict__ cnt_out,
    const int* __restrict__ nspill, const int* __restrict__ spill,
    const float* __restrict__ b1, float* __restrict__ h) {
  int row = (blockIdx.x * blockDim.x + threadIdx.x) >> 5;
  if (row >= NN) return;
  int lane = threadIdx.x & 31;
  int f = lane * 4;
  float4 q0 = *(const float4*)(b1 + f);
  float4 q1 = *(const float4*)(b1 + 128 + f);
  float4 q2 = *(const float4*)(b1 + 256 + f);
  float4 acc = make_float4(q0.x + q1.x + q2.x, q0.y + q1.y + q2.y,
                           q0.z + q1.z + q2.z, q0.w + q1.w + q2.w);
  int ns = min(*nspill, MAXSPILL);
  for (int r = 0; r < NREL; ++r) {
    const float* P = proj1 + (size_t)r * NN * 128;
    const int* co = cnt_out + r * NN;
    int deg = cnt_in[r * NN + row];
    int n = min(deg, CAP);
    const unsigned short* er = ell + ((size_t)r * NN + row) * CAP;
    float4 a0 = make_float4(0.f, 0.f, 0.f, 0.f);
    float4 a1 = make_float4(0.f, 0.f, 0.f, 0.f);
    int e = 0;
    for (; e + 1 < n; e += 2) {
      int s0 = er[e], s1 = er[e + 1];
      float w0 = rsqrtf((float)max(co[s0], 1));
      float w1 = rsqrtf((float)max(co[s1], 1));
      float4 v0 = *(const float4*)(P + (size_t)s0 * 128 + f);
      float4 v1 = *(const float4*)(P + (size_t)s1 * 128 + f);
      a0.x += w0 * v0.x; a0.y += w0 * v0.y; a0.z += w0 * v0.z; a0.w += w0 * v0.w;
      a1.x += w1 * v1.x; a1.y += w1 * v1.y; a1.z += w1 * v1.z; a1.w += w1 * v1.w;
    }
    if (e < n) {
      int s0 = er[e];
      float w0 = rsqrtf((float)max(co[s0], 1));
      float4 v0 = *(const float4*)(P + (size_t)s0 * 128 + f);
      a0.x += w0 * v0.x; a0.y += w0 * v0.y; a0.z += w0 * v0.z; a0.w += w0 * v0.w;
    }
    for (int i = 0; i < ns; ++i) {
      if (spill[3 * i] == r && spill[3 * i + 1] == row) {
        int s0 = spill[3 * i + 2];
        float w0 = rsqrtf((float)max(co[s0], 1));
        float4 v0 = *(const float4*)(P + (size_t)s0 * 128 + f);
        a0.x += w0 * v0.x; a0.y += w0 * v0.y; a0.z += w0 * v0.z; a0.w += w0 * v0.w;
      }
    }
    float si = rsqrtf((float)max(deg, 1));
    acc.x += (a0.x + a1.x) * si; acc.y += (a0.y + a1.y) * si;
    acc.z += (a0.z + a1.z) * si; acc.w += (a0.w + a1.w) * si;
  }
  acc.x = fmaxf(acc.x, 0.f); acc.y = fmaxf(acc.y, 0.f);
  acc.z = fmaxf(acc.z, 0.f); acc.w = fmaxf(acc.w, 0.f);
  *(float4*)(h + (size_t)row * 128 + f) = acc;
}

// fallback: per-relation L1 aggregate accumulating into h
template <bool FIRST, bool LAST>
__global__ __launch_bounds__(256) void agg1_one_kernel(
    const float* __restrict__ P, const unsigned short* __restrict__ ell_r,
    const int* __restrict__ ci, const int* __restrict__ co,
    const int* __restrict__ nspill, const int* __restrict__ spill,
    int rel, const float* __restrict__ b1, float* __restrict__ h) {
  int row = (blockIdx.x * blockDim.x + threadIdx.x) >> 5;
  if (row >= NN) return;
  int lane = threadIdx.x & 31;
  int f = lane * 4;
  int deg = ci[row];
  int n = min(deg, CAP);
  const unsigned short* er = ell_r + (size_t)row * CAP;
  float4 a0 = make_float4(0.f, 0.f, 0.f, 0.f);
  for (int e = 0; e < n; ++e) {
    int s0 = er[e];
    float w0 = rsqrtf((float)max(co[s0], 1));
    float4 v0 = *(const float4*)(P + (size_t)s0 * 128 + f);
    a0.x += w0 * v0.x; a0.y += w0 * v0.y; a0.z += w0 * v0.z; a0.w += w0 * v0.w;
  }
  int ns = min(*nspill, MAXSPILL);
  for (int i = 0; i < ns; ++i) {
    if (spill[3 * i] == rel && spill[3 * i + 1] == row) {
      int s0 = spill[3 * i + 2];
      float w0 = rsqrtf((float)max(co[s0], 1));
      float4 v0 = *(const float4*)(P + (size_t)s0 * 128 + f);
      a0.x += w0 * v0.x; a0.y += w0 * v0.y; a0.z += w0 * v0.z; a0.w += w0 * v0.w;
    }
  }
  float si = rsqrtf((float)max(deg, 1));
  float4 acc;
  if (FIRST) {
    float4 q0 = *(const float4*)(b1 + f);
    float4 q1 = *(const float4*)(b1 + 128 + f);
    float4 q2 = *(const float4*)(b1 + 256 + f);
    acc = make_float4(q0.x + q1.x + q2.x, q0.y + q1.y + q2.y,
                      q0.z + q1.z + q2.z, q0.w + q1.w + q2.w);
  } else {
    acc = *(const float4*)(h + (size_t)row * 128 + f);
  }
  acc.x += a0.x * si; acc.y += a0.y * si; acc.z += a0.z * si; acc.w += a0.w * si;
  if (LAST) {
    acc.x = fmaxf(acc.x, 0.f); acc.y = fmaxf(acc.y, 0.f);
    acc.z = fmaxf(acc.z, 0.f); acc.w = fmaxf(acc.w, 0.f);
  }
  *(float4*)(h + (size_t)row * 128 + f) = acc;
}

// ---- layer-2 aggregate, all 3 relations, bias fused; quarter-wave (16 lanes) per row ----
__global__ __launch_bounds__(256) void agg2_all_kernel(
    const float* __restrict__ proj2, const unsigned short* __restrict__ ell,
    const int* __restrict__ cnt_in,
    const int* __restrict__ nspill, const int* __restrict__ spill,
    const float* __restrict__ b2, float* __restrict__ out) {
  int row = (blockIdx.x * blockDim.x + threadIdx.x) >> 4;
  if (row >= NN) return;
  int lane = threadIdx.x & 15;
  int f = lane * 4;
  float4 q0 = *(const float4*)(b2 + f);
  float4 q1 = *(const float4*)(b2 + 64 + f);
  float4 q2 = *(const float4*)(b2 + 128 + f);
  float4 acc = make_float4(q0.x + q1.x + q2.x, q0.y + q1.y + q2.y,
                           q0.z + q1.z + q2.z, q0.w + q1.w + q2.w);
  int ns = min(*nspill, MAXSPILL);
  for (int r = 0; r < NREL; ++r) {
    const float* P = proj2 + (size_t)r * NN * 64;
    int deg = cnt_in[r * NN + row];
    int n = min(deg, CAP);
    const unsigned short* er = ell + ((size_t)r * NN + row) * CAP;
    float4 a0 = make_float4(0.f, 0.f, 0.f, 0.f);
    float4 a1 = make_float4(0.f, 0.f, 0.f, 0.f);
    int e = 0;
    for (; e + 1 < n; e += 2) {
      int s0 = er[e], s1 = er[e + 1];
      float4 v0 = *(const float4*)(P + (size_t)s0 * 64 + f);
      float4 v1 = *(const float4*)(P + (size_t)s1 * 64 + f);
      a0.x += v0.x; a0.y += v0.y; a0.z += v0.z; a0.w += v0.w;
      a1.x += v1.x; a1.y += v1.y; a1.z += v1.z; a1.w += v1.w;
    }
    if (e < n) {
      int s0 = er[e];
      float4 v0 = *(const float4*)(P + (size_t)s0 * 64 + f);
      a0.x += v0.x; a0.y += v0.y; a0.z += v0.z; a0.w += v0.w;
    }
    for (int i = 0; i < ns; ++i) {
      if (spill[3 * i] == r && spill[3 * i + 1] == row) {
        int s0 = spill[3 * i + 2];
        float4 v0 = *(const float4*)(P + (size_t)s0 * 64 + f);
        a0.x += v0.x; a0.y += v0.y; a0.z += v0.z; a0.w += v0.w;
      }
    }
    float si = rsqrtf((float)max(deg, 1));
    acc.x += (a0.x + a1.x) * si; acc.y += (a0.y + a1.y) * si;
    acc.z += (a0.z + a1.z) * si; acc.w += (a0.w + a1.w) * si;
  }
  *(float4*)(out + (size_t)row * 64 + f) = acc;
}

// fallback: per-relation L2 aggregate into out
template <bool FIRST>
__global__ __launch_bounds__(256) void agg2_one_kernel(
    const float* __restrict__ P, const unsigned short* __restrict__ ell_r,
    const int* __restrict__ ci,
    const int* __restrict__ nspill, const int* __restrict__ spill,
    int rel, const float* __restrict__ b2, float* __restrict__ out) {
  int row = (blockIdx.x * blockDim.x + threadIdx.x) >> 4;
  if (row >= NN) return;
  int lane = threadIdx.x & 15;
  int f = lane * 4;
  int deg = ci[row];
  int n = min(deg, CAP);
  const unsigned short* er = ell_r + (size_t)row * CAP;
  float4 a0 = make_float4(0.f, 0.f, 0.f, 0.f);
  for (int e = 0; e < n; ++e) {
    int s0 = er[e];
    float4 v0 = *(const float4*)(P + (size_t)s0 * 64 + f);
    a0.x += v0.x; a0.y += v0.y; a0.z += v0.z; a0.w += v0.w;
  }
  int ns = min(*nspill, MAXSPILL);
  for (int i = 0; i < ns; ++i) {
    if (spill[3 * i] == rel && spill[3 * i + 1] == row) {
      int s0 = spill[3 * i + 2];
      float4 v0 = *(const float4*)(P + (size_t)s0 * 64 + f);
      a0.x += v0.x; a0.y += v0.y; a0.z += v0.z; a0.w += v0.w;
    }
  }
  float si = rsqrtf((float)max(deg, 1));
  float4 acc;
  if (FIRST) {
    float4 q0 = *(const float4*)(b2 + f);
    float4 q1 = *(const float4*)(b2 + 64 + f);
    float4 q2 = *(const float4*)(b2 + 128 + f);
    acc = make_float4(q0.x + q1.x + q2.x, q0.y + q1.y + q2.y,
                      q0.z + q1.z + q2.z, q0.w + q1.w + q2.w);
  } else {
    acc = *(const float4*)(out + (size_t)row * 64 + f);
  }
  acc.x += a0.x * si; acc.y += a0.y * si; acc.z += a0.z * si; acc.w += a0.w * si;
  *(float4*)(out + (size_t)row * 64 + f) = acc;
}

extern "C" void kernel_launch(void* const* d_in, const int* in_sizes, int n_in,
                              void* d_out, int out_size, void* d_ws, size_t ws_size,
                              hipStream_t stream) {
  const float* x   = (const float*)d_in[0];
  const int* edges = (const int*)d_in[1];
  const float* W1  = (const float*)d_in[2];
  const float* b1  = (const float*)d_in[3];
  const float* W2  = (const float*)d_in[4];
  const float* b2  = (const float*)d_in[5];
  float* out = (float*)d_out;
  char* wsb = (char*)d_ws;

  const size_t PROJ1_FULL = (size_t)NREL * NN * 128 * 4;  // 76.8 MB
  const size_t PROJ1_ONE  = (size_t)NN * 128 * 4;         // 25.6 MB
  const size_t H_BYTES    = (size_t)NN * 128 * 4;         // 25.6 MB
  const size_t ELL_BYTES  = (size_t)NREL * NN * CAP * 2;  // 7.2 MB
  const size_t CNT_BYTES  = (size_t)NREL * NN * 4;        // 0.6 MB
  const size_t FULL_NEED = PROJ1_FULL + H_BYTES + ELL_BYTES + 2 * CNT_BYTES + 16 + 3 * MAXSPILL * 4;
  bool full = ws_size >= FULL_NEED;

  size_t projBytes = full ? PROJ1_FULL : PROJ1_ONE;
  float* proj = (float*)wsb;                               // proj1 (and proj2 reuse)
  float* h    = (float*)(wsb + projBytes);
  unsigned short* ell = (unsigned short*)(wsb + projBytes + H_BYTES);
  int* cnt_out = (int*)(wsb + projBytes + H_BYTES + ELL_BYTES);
  int* cnt_in  = cnt_out + NREL * NN;
  int* nspill  = cnt_in + NREL * NN;
  int* spill   = nspill + 4;

  // zero counters + spill count
  hipMemsetAsync(cnt_out, 0, 2 * CNT_BYTES + 16, stream);

  const int agg1Blocks = (NN * 32 + 255) / 256;
  const int agg2Blocks = (NN * 16 + 255) / 256;

  if (full) {
    // build + all 3 L1 projections in one launch (build blocks first)
    fused_build_gemm1_kernel<<<BB + GEMM1_BLKS, 256, 0, stream>>>(
        edges, cnt_out, cnt_in, ell, nspill, spill, x, W1, proj);
    agg1_all_kernel<<<agg1Blocks, 256, 0, stream>>>(
        proj, ell, cnt_in, cnt_out, nspill, spill, b1, h);
    gemm2_kernel<<<dim3(G1X, 1, NREL), 256, 0, stream>>>(h, W2, cnt_out, proj, NN * 64);
    agg2_all_kernel<<<agg2Blocks, 256, 0, stream>>>(
        proj, ell, cnt_in, nspill, spill, b2, out);
  } else {
    // sequential fallback: one proj buffer, per-relation agg
    fused_build_gemm1_kernel<<<BB, 256, 0, stream>>>(
        edges, cnt_out, cnt_in, ell, nspill, spill, x, W1, proj);
    for (int r = 0; r < NREL; ++r) {
      gemm1_single_kernel<<<dim3(G1X, 2), 256, 0, stream>>>(
          x, W1 + (size_t)r * 128 * 128, proj);
      unsigned short* ell_r = ell + (size_t)r * NN * CAP;
      if (r == 0)
        agg1_one_kernel<true, false><<<agg1Blocks, 256, 0, stream>>>(
            proj, ell_r, cnt_in + r * NN, cnt_out + r * NN, nspill, spill, r, b1, h);
      else if (r == 1)
        agg1_one_kernel<false, false><<<agg1Blocks, 256, 0, stream>>>(
            proj, ell_r, cnt_in + r * NN, cnt_out + r * NN, nspill, spill, r, b1, h);
      else
        agg1_one_kernel<false, true><<<agg1Blocks, 256, 0, stream>>>(
            proj, ell_r, cnt_in + r * NN, cnt_out + r * NN, nspill, spill, r, b1, h);
    }
    for (int r = 0; r < NREL; ++r) {
      gemm2_kernel<<<dim3(G1X, 1, 1), 256, 0, stream>>>(
          h, W2 + (size_t)r * 128 * 64, cnt_out + r * NN, proj, 0);
      unsigned short* ell_r = ell + (size_t)r * NN * CAP;
      if (r == 0)
        agg2_one_kernel<true><<<agg2Blocks, 256, 0, stream>>>(
            proj, ell_r, cnt_in + r * NN, nspill, spill, r, b2, out);
      else
        agg2_one_kernel<false><<<agg2Blocks, 256, 0, stream>>>(
            proj, ell_r, cnt_in + r * NN, nspill, spill, r, b2, out);
    }
  }
}

// Round 5
// 371.914 us; speedup vs baseline: 3.0576x; 1.2222x over previous
//
#include <hip/hip_runtime.h>

constexpr int NN = 50000;
constexpr int NREL = 3;
constexpr int NE = 400000;
constexpr int CAP = 24;        // ELL capacity; Poisson(8) tail at 24 ~ 4e-9/node
constexpr int MAXSPILL = 4096;

constexpr int G1X = (NN + 63) / 64;           // 782 row-tiles
constexpr int GEMM1_BLKS = G1X * 2 * NREL;    // 4692 blocks; >= 4688 edge chunks
constexpr int LDA = 132;                      // +4 pad: kills 4-way bank conflict on As reads

// ---- plain GEMM tile body: C[M][N] = (A * rsqrt(cnt)?) @ W, 64x64 tile, K=128 ----
template <bool SCALE>
__device__ __forceinline__ void gemm_body(
    const float* __restrict__ A, const float* __restrict__ W,
    const int* __restrict__ cnt_scale, float* __restrict__ C,
    int M, int N, int row0, int col0) {
  __shared__ float As[64][LDA];
  __shared__ float Bs[128][64];
  int t = threadIdx.x;
#pragma unroll
  for (int i = 0; i < 8; ++i) {
    int idx = t + i * 256;
    int r = idx >> 5;
    int c4 = (idx & 31) << 2;
    int grow = row0 + r;
    float4 v = make_float4(0.f, 0.f, 0.f, 0.f);
    if (grow < M) {
      v = *(const float4*)(A + (size_t)grow * 128 + c4);
      if (SCALE) {
        float s = rsqrtf((float)max(cnt_scale[grow], 1));
        v.x *= s; v.y *= s; v.z *= s; v.w *= s;
      }
    }
    *(float4*)(&As[r][c4]) = v;
  }
#pragma unroll
  for (int i = 0; i < 8; ++i) {
    int idx = t + i * 256;
    int k = idx >> 4;
    int c4 = (idx & 15) << 2;
    *(float4*)(&Bs[k][c4]) = *(const float4*)(W + (size_t)k * N + col0 + c4);
  }
  __syncthreads();
  int tx4 = (t & 15) << 2;
  int ty4 = (t >> 4) << 2;
  float acc[4][4] = {};
#pragma unroll 8
  for (int k = 0; k < 128; k += 4) {
    float4 b0 = *(const float4*)(&Bs[k + 0][tx4]);
    float4 b1 = *(const float4*)(&Bs[k + 1][tx4]);
    float4 b2 = *(const float4*)(&Bs[k + 2][tx4]);
    float4 b3 = *(const float4*)(&Bs[k + 3][tx4]);
#pragma unroll
    for (int m = 0; m < 4; ++m) {
      float4 a = *(const float4*)(&As[ty4 + m][k]);
      acc[m][0] += a.x * b0.x + a.y * b1.x + a.z * b2.x + a.w * b3.x;
      acc[m][1] += a.x * b0.y + a.y * b1.y + a.z * b2.y + a.w * b3.y;
      acc[m][2] += a.x * b0.z + a.y * b1.z + a.z * b2.z + a.w * b3.z;
      acc[m][3] += a.x * b0.w + a.y * b1.w + a.z * b2.w + a.w * b3.w;
    }
  }
#pragma unroll
  for (int m = 0; m < 4; ++m) {
    int row = row0 + ty4 + m;
    if (row < M)
      *(float4*)(C + (size_t)row * N + col0 + tx4) =
          make_float4(acc[m][0], acc[m][1], acc[m][2], acc[m][3]);
  }
}

// ---- fused: every block = 1 GEMM tile of proj1_r = x@W1_r  PLUS  256 edges of ELL build.
// Atomics issued right AFTER the staging barrier (so the barrier drain doesn't wait them),
// consumed after the K-loop -> latency hidden under 2048 FMAs/thread.
__global__ __launch_bounds__(256) void fused_build_gemm1_kernel(
    const int* __restrict__ edges, int* __restrict__ cnt_out, int* __restrict__ cnt_in,
    unsigned short* __restrict__ ell, int* __restrict__ nspill, int* __restrict__ spill,
    const float* __restrict__ x, const float* __restrict__ W1, float* __restrict__ proj1) {
  __shared__ float As[64][LDA];
  __shared__ float Bs[128][64];
  int t = threadIdx.x;

  // --- edge slice: plain loads of endpoints (waited at the staging barrier, cheap) ---
  int eg = blockIdx.x * 256 + t;
  bool have = (eg < NREL * NE);
  int er = 0, es = 0, ed = 0;
  if (have) {
    er = eg / NE;
    int e = eg - er * NE;
    const int* b = edges + (size_t)er * 2 * NE;
    es = b[e];
    ed = b[NE + e];
  }

  // --- GEMM tile mapping ---
  int g = blockIdx.x;
  int r = g / (G1X * 2);
  int rem = g - r * (G1X * 2);
  int row0 = (rem >> 1) * 64;
  int col0 = (rem & 1) * 64;
  const float* W = W1 + (size_t)r * 128 * 128;
  float* C = proj1 + (size_t)r * NN * 128;

  // staging
#pragma unroll
  for (int i = 0; i < 8; ++i) {
    int idx = t + i * 256;
    int rr = idx >> 5;
    int c4 = (idx & 31) << 2;
    int grow = row0 + rr;
    float4 v = make_float4(0.f, 0.f, 0.f, 0.f);
    if (grow < NN) v = *(const float4*)(x + (size_t)grow * 128 + c4);
    *(float4*)(&As[rr][c4]) = v;
  }
#pragma unroll
  for (int i = 0; i < 8; ++i) {
    int idx = t + i * 256;
    int k = idx >> 4;
    int c4 = (idx & 15) << 2;
    *(float4*)(&Bs[k][c4]) = *(const float4*)(W + (size_t)k * 128 + col0 + c4);
  }
  __syncthreads();

  // --- issue atomics now; results consumed only after the K-loop ---
  int pos = 0;
  if (have) {
    atomicAdd(cnt_out + er * NN + es, 1);                 // no return needed
    pos = atomicAdd(cnt_in + er * NN + ed, 1);            // return hidden under K-loop
  }

  int tx4 = (t & 15) << 2;
  int ty4 = (t >> 4) << 2;
  float acc[4][4] = {};
#pragma unroll 8
  for (int k = 0; k < 128; k += 4) {
    float4 b0 = *(const float4*)(&Bs[k + 0][tx4]);
    float4 b1 = *(const float4*)(&Bs[k + 1][tx4]);
    float4 b2 = *(const float4*)(&Bs[k + 2][tx4]);
    float4 b3 = *(const float4*)(&Bs[k + 3][tx4]);
#pragma unroll
    for (int m = 0; m < 4; ++m) {
      float4 a = *(const float4*)(&As[ty4 + m][k]);
      acc[m][0] += a.x * b0.x + a.y * b1.x + a.z * b2.x + a.w * b3.x;
      acc[m][1] += a.x * b0.y + a.y * b1.y + a.z * b2.y + a.w * b3.y;
      acc[m][2] += a.x * b0.z + a.y * b1.z + a.z * b2.z + a.w * b3.z;
      acc[m][3] += a.x * b0.w + a.y * b1.w + a.z * b2.w + a.w * b3.w;
    }
  }
#pragma unroll
  for (int m = 0; m < 4; ++m) {
    int row = row0 + ty4 + m;
    if (row < NN)
      *(float4*)(C + (size_t)row * 128 + col0 + tx4) =
          make_float4(acc[m][0], acc[m][1], acc[m][2], acc[m][3]);
  }

  // --- consume atomic result ---
  if (have) {
    if (pos < CAP) {
      ell[((size_t)er * NN + ed) * CAP + pos] = (unsigned short)es;
    } else {
      int i = atomicAdd(nspill, 1);
      if (i < MAXSPILL) { spill[3 * i] = er; spill[3 * i + 1] = ed; spill[3 * i + 2] = es; }
    }
  }
}

// standalone GEMMs (fallback path / layer 2)
__global__ __launch_bounds__(256) void gemm1_single_kernel(
    const float* __restrict__ x, const float* __restrict__ W1r, float* __restrict__ proj) {
  gemm_body<false>(x, W1r, nullptr, proj, NN, 128, blockIdx.x * 64, blockIdx.y * 64);
}
__global__ __launch_bounds__(256) void gemm2_kernel(
    const float* __restrict__ h, const float* __restrict__ W2,
    const int* __restrict__ cnt_out, float* __restrict__ proj2, int relStride) {
  int r = blockIdx.z;
  gemm_body<true>(h, W2 + (size_t)r * 128 * 64, cnt_out + r * NN,
                  proj2 + (size_t)r * relStride, NN, 64, blockIdx.x * 64, 0);
}

// fallback build-only kernel
__global__ void ell_build_kernel(const int* __restrict__ edges,
                                 int* __restrict__ cnt_out, int* __restrict__ cnt_in,
                                 unsigned short* __restrict__ ell,
                                 int* __restrict__ nspill, int* __restrict__ spill) {
  int gid = blockIdx.x * blockDim.x + threadIdx.x;
  if (gid >= NREL * NE) return;
  int r = gid / NE;
  int e = gid - r * NE;
  const int* b = edges + (size_t)r * 2 * NE;
  int s = b[e];
  int d = b[NE + e];
  atomicAdd(cnt_out + r * NN + s, 1);
  int pos = atomicAdd(cnt_in + r * NN + d, 1);
  if (pos < CAP) {
    ell[((size_t)r * NN + d) * CAP + pos] = (unsigned short)s;
  } else {
    int i = atomicAdd(nspill, 1);
    if (i < MAXSPILL) { spill[3 * i] = r; spill[3 * i + 1] = d; spill[3 * i + 2] = s; }
  }
}

// ---- layer-1 aggregate, all 3 relations, bias+relu fused; half-wave (32 lanes) per row ----
__global__ __launch_bounds__(256) void agg1_all_kernel(
    const float* __restrict__ proj1, const unsigned short* __restrict__ ell,
    const int* __restrict__ cnt_in, const int* __restrict__ cnt_out,
    const int* __restrict__ nspill, const int* __restrict__ spill,
    const float* __restrict__ b1, float* __restrict__ h) {
  int row = (blockIdx.x * blockDim.x + threadIdx.x) >> 5;
  if (row >= NN) return;
  int lane = threadIdx.x & 31;
  int f = lane * 4;
  float4 q0 = *(const float4*)(b1 + f);
  float4 q1 = *(const float4*)(b1 + 128 + f);
  float4 q2 = *(const float4*)(b1 + 256 + f);
  float4 acc = make_float4(q0.x + q1.x + q2.x, q0.y + q1.y + q2.y,
                           q0.z + q1.z + q2.z, q0.w + q1.w + q2.w);
  int ns = min(*nspill, MAXSPILL);
  for (int r = 0; r < NREL; ++r) {
    const float* P = proj1 + (size_t)r * NN * 128;
    const int* co = cnt_out + r * NN;
    int deg = cnt_in[r * NN + row];
    int n = min(deg, CAP);
    const unsigned short* er = ell + ((size_t)r * NN + row) * CAP;
    float4 a0 = make_float4(0.f, 0.f, 0.f, 0.f);
    float4 a1 = make_float4(0.f, 0.f, 0.f, 0.f);
    int e = 0;
    for (; e + 1 < n; e += 2) {
      int s0 = er[e], s1 = er[e + 1];
      float w0 = rsqrtf((float)max(co[s0], 1));
      float w1 = rsqrtf((float)max(co[s1], 1));
      float4 v0 = *(const float4*)(P + (size_t)s0 * 128 + f);
      float4 v1 = *(const float4*)(P + (size_t)s1 * 128 + f);
      a0.x += w0 * v0.x; a0.y += w0 * v0.y; a0.z += w0 * v0.z; a0.w += w0 * v0.w;
      a1.x += w1 * v1.x; a1.y += w1 * v1.y; a1.z += w1 * v1.z; a1.w += w1 * v1.w;
    }
    if (e < n) {
      int s0 = er[e];
      float w0 = rsqrtf((float)max(co[s0], 1));
      float4 v0 = *(const float4*)(P + (size_t)s0 * 128 + f);
      a0.x += w0 * v0.x; a0.y += w0 * v0.y; a0.z += w0 * v0.z; a0.w += w0 * v0.w;
    }
    for (int i = 0; i < ns; ++i) {
      if (spill[3 * i] == r && spill[3 * i + 1] == row) {
        int s0 = spill[3 * i + 2];
        float w0 = rsqrtf((float)max(co[s0], 1));
        float4 v0 = *(const float4*)(P + (size_t)s0 * 128 + f);
        a0.x += w0 * v0.x; a0.y += w0 * v0.y; a0.z += w0 * v0.z; a0.w += w0 * v0.w;
      }
    }
    float si = rsqrtf((float)max(deg, 1));
    acc.x += (a0.x + a1.x) * si; acc.y += (a0.y + a1.y) * si;
    acc.z += (a0.z + a1.z) * si; acc.w += (a0.w + a1.w) * si;
  }
  acc.x = fmaxf(acc.x, 0.f); acc.y = fmaxf(acc.y, 0.f);
  acc.z = fmaxf(acc.z, 0.f); acc.w = fmaxf(acc.w, 0.f);
  *(float4*)(h + (size_t)row * 128 + f) = acc;
}

// fallback: per-relation L1 aggregate accumulating into h
template <bool FIRST, bool LAST>
__global__ __launch_bounds__(256) void agg1_one_kernel(
    const float* __restrict__ P, const unsigned short* __restrict__ ell_r,
    const int* __restrict__ ci, const int* __restrict__ co,
    const int* __restrict__ nspill, const int* __restrict__ spill,
    int rel, const float* __restrict__ b1, float* __restrict__ h) {
  int row = (blockIdx.x * blockDim.x + threadIdx.x) >> 5;
  if (row >= NN) return;
  int lane = threadIdx.x & 31;
  int f = lane * 4;
  int deg = ci[row];
  int n = min(deg, CAP);
  const unsigned short* er = ell_r + (size_t)row * CAP;
  float4 a0 = make_float4(0.f, 0.f, 0.f, 0.f);
  for (int e = 0; e < n; ++e) {
    int s0 = er[e];
    float w0 = rsqrtf((float)max(co[s0], 1));
    float4 v0 = *(const float4*)(P + (size_t)s0 * 128 + f);
    a0.x += w0 * v0.x; a0.y += w0 * v0.y; a0.z += w0 * v0.z; a0.w += w0 * v0.w;
  }
  int ns = min(*nspill, MAXSPILL);
  for (int i = 0; i < ns; ++i) {
    if (spill[3 * i] == rel && spill[3 * i + 1] == row) {
      int s0 = spill[3 * i + 2];
      float w0 = rsqrtf((float)max(co[s0], 1));
      float4 v0 = *(const float4*)(P + (size_t)s0 * 128 + f);
      a0.x += w0 * v0.x; a0.y += w0 * v0.y; a0.z += w0 * v0.z; a0.w += w0 * v0.w;
    }
  }
  float si = rsqrtf((float)max(deg, 1));
  float4 acc;
  if (FIRST) {
    float4 q0 = *(const float4*)(b1 + f);
    float4 q1 = *(const float4*)(b1 + 128 + f);
    float4 q2 = *(const float4*)(b1 + 256 + f);
    acc = make_float4(q0.x + q1.x + q2.x, q0.y + q1.y + q2.y,
                      q0.z + q1.z + q2.z, q0.w + q1.w + q2.w);
  } else {
    acc = *(const float4*)(h + (size_t)row * 128 + f);
  }
  acc.x += a0.x * si; acc.y += a0.y * si; acc.z += a0.z * si; acc.w += a0.w * si;
  if (LAST) {
    acc.x = fmaxf(acc.x, 0.f); acc.y = fmaxf(acc.y, 0.f);
    acc.z = fmaxf(acc.z, 0.f); acc.w = fmaxf(acc.w, 0.f);
  }
  *(float4*)(h + (size_t)row * 128 + f) = acc;
}

// ---- layer-2 aggregate, all 3 relations, bias fused; quarter-wave (16 lanes) per row ----
__global__ __launch_bounds__(256) void agg2_all_kernel(
    const float* __restrict__ proj2, const unsigned short* __restrict__ ell,
    const int* __restrict__ cnt_in,
    const int* __restrict__ nspill, const int* __restrict__ spill,
    const float* __restrict__ b2, float* __restrict__ out) {
  int row = (blockIdx.x * blockDim.x + threadIdx.x) >> 4;
  if (row >= NN) return;
  int lane = threadIdx.x & 15;
  int f = lane * 4;
  float4 q0 = *(const float4*)(b2 + f);
  float4 q1 = *(const float4*)(b2 + 64 + f);
  float4 q2 = *(const float4*)(b2 + 128 + f);
  float4 acc = make_float4(q0.x + q1.x + q2.x, q0.y + q1.y + q2.y,
                           q0.z + q1.z + q2.z, q0.w + q1.w + q2.w);
  int ns = min(*nspill, MAXSPILL);
  for (int r = 0; r < NREL; ++r) {
    const float* P = proj2 + (size_t)r * NN * 64;
    int deg = cnt_in[r * NN + row];
    int n = min(deg, CAP);
    const unsigned short* er = ell + ((size_t)r * NN + row) * CAP;
    float4 a0 = make_float4(0.f, 0.f, 0.f, 0.f);
    float4 a1 = make_float4(0.f, 0.f, 0.f, 0.f);
    int e = 0;
    for (; e + 1 < n; e += 2) {
      int s0 = er[e], s1 = er[e + 1];
      float4 v0 = *(const float4*)(P + (size_t)s0 * 64 + f);
      float4 v1 = *(const float4*)(P + (size_t)s1 * 64 + f);
      a0.x += v0.x; a0.y += v0.y; a0.z += v0.z; a0.w += v0.w;
      a1.x += v1.x; a1.y += v1.y; a1.z += v1.z; a1.w += v1.w;
    }
    if (e < n) {
      int s0 = er[e];
      float4 v0 = *(const float4*)(P + (size_t)s0 * 64 + f);
      a0.x += v0.x; a0.y += v0.y; a0.z += v0.z; a0.w += v0.w;
    }
    for (int i = 0; i < ns; ++i) {
      if (spill[3 * i] == r && spill[3 * i + 1] == row) {
        int s0 = spill[3 * i + 2];
        float4 v0 = *(const float4*)(P + (size_t)s0 * 64 + f);
        a0.x += v0.x; a0.y += v0.y; a0.z += v0.z; a0.w += v0.w;
      }
    }
    float si = rsqrtf((float)max(deg, 1));
    acc.x += (a0.x + a1.x) * si; acc.y += (a0.y + a1.y) * si;
    acc.z += (a0.z + a1.z) * si; acc.w += (a0.w + a1.w) * si;
  }
  *(float4*)(out + (size_t)row * 64 + f) = acc;
}

// fallback: per-relation L2 aggregate into out
template <bool FIRST>
__global__ __launch_bounds__(256) void agg2_one_kernel(
    const float* __restrict__ P, const unsigned short* __restrict__ ell_r,
    const int* __restrict__ ci,
    const int* __restrict__ nspill, const int* __restrict__ spill,
    int rel, const float* __restrict__ b2, float* __restrict__ out) {
  int row = (blockIdx.x * blockDim.x + threadIdx.x) >> 4;
  if (row >= NN) return;
  int lane = threadIdx.x & 15;
  int f = lane * 4;
  int deg = ci[row];
  int n = min(deg, CAP);
  const unsigned short* er = ell_r + (size_t)row * CAP;
  float4 a0 = make_float4(0.f, 0.f, 0.f, 0.f);
  for (int e = 0; e < n; ++e) {
    int s0 = er[e];
    float4 v0 = *(const float4*)(P + (size_t)s0 * 64 + f);
    a0.x += v0.x; a0.y += v0.y; a0.z += v0.z; a0.w += v0.w;
  }
  int ns = min(*nspill, MAXSPILL);
  for (int i = 0; i < ns; ++i) {
    if (spill[3 * i] == rel && spill[3 * i + 1] == row) {
      int s0 = spill[3 * i + 2];
      float4 v0 = *(const float4*)(P + (size_t)s0 * 64 + f);
      a0.x += v0.x; a0.y += v0.y; a0.z += v0.z; a0.w += v0.w;
    }
  }
  float si = rsqrtf((float)max(deg, 1));
  float4 acc;
  if (FIRST) {
    float4 q0 = *(const float4*)(b2 + f);
    float4 q1 = *(const float4*)(b2 + 64 + f);
    float4 q2 = *(const float4*)(b2 + 128 + f);
    acc = make_float4(q0.x + q1.x + q2.x, q0.y + q1.y + q2.y,
                      q0.z + q1.z + q2.z, q0.w + q1.w + q2.w);
  } else {
    acc = *(const float4*)(out + (size_t)row * 64 + f);
  }
  acc.x += a0.x * si; acc.y += a0.y * si; acc.z += a0.z * si; acc.w += a0.w * si;
  *(float4*)(out + (size_t)row * 64 + f) = acc;
}

extern "C" void kernel_launch(void* const* d_in, const int* in_sizes, int n_in,
                              void* d_out, int out_size, void* d_ws, size_t ws_size,
                              hipStream_t stream) {
  const float* x   = (const float*)d_in[0];
  const int* edges = (const int*)d_in[1];
  const float* W1  = (const float*)d_in[2];
  const float* b1  = (const float*)d_in[3];
  const float* W2  = (const float*)d_in[4];
  const float* b2  = (const float*)d_in[5];
  float* out = (float*)d_out;
  char* wsb = (char*)d_ws;

  const size_t PROJ1_FULL = (size_t)NREL * NN * 128 * 4;  // 76.8 MB
  const size_t PROJ1_ONE  = (size_t)NN * 128 * 4;         // 25.6 MB
  const size_t H_BYTES    = (size_t)NN * 128 * 4;         // 25.6 MB
  const size_t ELL_BYTES  = (size_t)NREL * NN * CAP * 2;  // 7.2 MB
  const size_t CNT_BYTES  = (size_t)NREL * NN * 4;        // 0.6 MB
  const size_t FULL_NEED = PROJ1_FULL + H_BYTES + ELL_BYTES + 2 * CNT_BYTES + 16 + 3 * MAXSPILL * 4;
  bool full = ws_size >= FULL_NEED;

  size_t projBytes = full ? PROJ1_FULL : PROJ1_ONE;
  float* proj = (float*)wsb;                               // proj1 (and proj2 reuse)
  float* h    = (float*)(wsb + projBytes);
  unsigned short* ell = (unsigned short*)(wsb + projBytes + H_BYTES);
  int* cnt_out = (int*)(wsb + projBytes + H_BYTES + ELL_BYTES);
  int* cnt_in  = cnt_out + NREL * NN;
  int* nspill  = cnt_in + NREL * NN;
  int* spill   = nspill + 4;

  // zero counters + spill count
  hipMemsetAsync(cnt_out, 0, 2 * CNT_BYTES + 16, stream);

  const int agg1Blocks = (NN * 32 + 255) / 256;
  const int agg2Blocks = (NN * 16 + 255) / 256;

  if (full) {
    // intra-block fused: each block = 1 GEMM tile + 256 edges (atomics hidden under K-loop)
    fused_build_gemm1_kernel<<<GEMM1_BLKS, 256, 0, stream>>>(
        edges, cnt_out, cnt_in, ell, nspill, spill, x, W1, proj);
    agg1_all_kernel<<<agg1Blocks, 256, 0, stream>>>(
        proj, ell, cnt_in, cnt_out, nspill, spill, b1, h);
    gemm2_kernel<<<dim3(G1X, 1, NREL), 256, 0, stream>>>(h, W2, cnt_out, proj, NN * 64);
    agg2_all_kernel<<<agg2Blocks, 256, 0, stream>>>(
        proj, ell, cnt_in, nspill, spill, b2, out);
  } else {
    // sequential fallback: one proj buffer, per-relation agg
    ell_build_kernel<<<(NREL * NE + 255) / 256, 256, 0, stream>>>(
        edges, cnt_out, cnt_in, ell, nspill, spill);
    for (int r = 0; r < NREL; ++r) {
      gemm1_single_kernel<<<dim3(G1X, 2), 256, 0, stream>>>(
          x, W1 + (size_t)r * 128 * 128, proj);
      unsigned short* ell_r = ell + (size_t)r * NN * CAP;
      if (r == 0)
        agg1_one_kernel<true, false><<<agg1Blocks, 256, 0, stream>>>(
            proj, ell_r, cnt_in + r * NN, cnt_out + r * NN, nspill, spill, r, b1, h);
      else if (r == 1)
        agg1_one_kernel<false, false><<<agg1Blocks, 256, 0, stream>>>(
            proj, ell_r, cnt_in + r * NN, cnt_out + r * NN, nspill, spill, r, b1, h);
      else
        agg1_one_kernel<false, true><<<agg1Blocks, 256, 0, stream>>>(
            proj, ell_r, cnt_in + r * NN, cnt_out + r * NN, nspill, spill, r, b1, h);
    }
    for (int r = 0; r < NREL; ++r) {
      gemm2_kernel<<<dim3(G1X, 1, 1), 256, 0, stream>>>(
          h, W2 + (size_t)r * 128 * 64, cnt_out + r * NN, proj, 0);
      unsigned short* ell_r = ell + (size_t)r * NN * CAP;
      if (r == 0)
        agg2_one_kernel<true><<<agg2Blocks, 256, 0, stream>>>(
            proj, ell_r, cnt_in + r * NN, nspill, spill, r, b2, out);
      else
        agg2_one_kernel<false><<<agg2Blocks, 256, 0, stream>>>(
            proj, ell_r, cnt_in + r * NN, nspill, spill, r, b2, out);
    }
  }
}

// Round 6
// 310.764 us; speedup vs baseline: 3.6592x; 1.1968x over previous
//
#include <hip/hip_runtime.h>

constexpr int NN = 50000;
constexpr int NREL = 3;
constexpr int NE = 400000;
constexpr int CAP = 24;        // ELL capacity; Poisson(8) tail at 24 ~ 4e-9/node
constexpr int MAXSPILL = 4096;

constexpr int G1X = (NN + 63) / 64;           // 782 row-tiles
constexpr int GEMM1_BLKS = G1X * 2 * NREL;    // 4692 blocks; >= 4688 edge chunks
constexpr int LDA = 68;                       // BK=64 + 4 pad

// ---- GEMM tile body, BK=64 two-stage: C[M][N] = (A * rsqrt(cnt)?) @ W ----
// LDS: As[64][68] + Bs[64][64] = 33.8 KB -> 3 blocks/CU at launch_bounds(256,3)
template <bool SCALE>
__device__ __forceinline__ void gemm_body(
    const float* __restrict__ A, const float* __restrict__ W,
    const int* __restrict__ cnt_scale, float* __restrict__ C,
    int M, int N, int row0, int col0) {
  __shared__ float As[64][LDA];
  __shared__ float Bs[64][64];
  int t = threadIdx.x;
  int tx4 = (t & 15) << 2;
  int ty4 = (t >> 4) << 2;
  float acc[4][4] = {};
  for (int k0 = 0; k0 < 128; k0 += 64) {
    if (k0) __syncthreads();
#pragma unroll
    for (int i = 0; i < 4; ++i) {
      int idx = t + i * 256;             // 1024 float4 slots
      int r = idx >> 4;
      int c4 = (idx & 15) << 2;
      int grow = row0 + r;
      float4 v = make_float4(0.f, 0.f, 0.f, 0.f);
      if (grow < M) {
        v = *(const float4*)(A + (size_t)grow * 128 + k0 + c4);
        if (SCALE) {
          float s = rsqrtf((float)max(cnt_scale[grow], 1));
          v.x *= s; v.y *= s; v.z *= s; v.w *= s;
        }
      }
      *(float4*)(&As[r][c4]) = v;
    }
#pragma unroll
    for (int i = 0; i < 4; ++i) {
      int idx = t + i * 256;
      int k = idx >> 4;
      int c4 = (idx & 15) << 2;
      *(float4*)(&Bs[k][c4]) = *(const float4*)(W + (size_t)(k0 + k) * N + col0 + c4);
    }
    __syncthreads();
#pragma unroll 8
    for (int k = 0; k < 64; k += 4) {
      float4 b0 = *(const float4*)(&Bs[k + 0][tx4]);
      float4 b1 = *(const float4*)(&Bs[k + 1][tx4]);
      float4 b2 = *(const float4*)(&Bs[k + 2][tx4]);
      float4 b3 = *(const float4*)(&Bs[k + 3][tx4]);
#pragma unroll
      for (int m = 0; m < 4; ++m) {
        float4 a = *(const float4*)(&As[ty4 + m][k]);
        acc[m][0] += a.x * b0.x + a.y * b1.x + a.z * b2.x + a.w * b3.x;
        acc[m][1] += a.x * b0.y + a.y * b1.y + a.z * b2.y + a.w * b3.y;
        acc[m][2] += a.x * b0.z + a.y * b1.z + a.z * b2.z + a.w * b3.z;
        acc[m][3] += a.x * b0.w + a.y * b1.w + a.z * b2.w + a.w * b3.w;
      }
    }
  }
#pragma unroll
  for (int m = 0; m < 4; ++m) {
    int row = row0 + ty4 + m;
    if (row < M)
      *(float4*)(C + (size_t)row * N + col0 + tx4) =
          make_float4(acc[m][0], acc[m][1], acc[m][2], acc[m][3]);
  }
}

// ---- fused: every block = 1 GEMM tile of proj1_r = x@W1_r  PLUS  256 edges of ELL build.
// Atomics issued right after the first staging barrier, consumed at kernel end.
__global__ __launch_bounds__(256, 3) void fused_build_gemm1_kernel(
    const int* __restrict__ edges, int* __restrict__ cnt_out, int* __restrict__ cnt_in,
    unsigned short* __restrict__ ell, int* __restrict__ nspill, int* __restrict__ spill,
    const float* __restrict__ x, const float* __restrict__ W1, float* __restrict__ proj1) {
  __shared__ float As[64][LDA];
  __shared__ float Bs[64][64];
  int t = threadIdx.x;

  // --- edge slice ---
  int eg = blockIdx.x * 256 + t;
  bool have = (eg < NREL * NE);
  int er = 0, es = 0, ed = 0;
  if (have) {
    er = eg / NE;
    int e = eg - er * NE;
    const int* b = edges + (size_t)er * 2 * NE;
    es = b[e];
    ed = b[NE + e];
  }

  // --- GEMM tile mapping ---
  int g = blockIdx.x;
  int r = g / (G1X * 2);
  int rem = g - r * (G1X * 2);
  int row0 = (rem >> 1) * 64;
  int col0 = (rem & 1) * 64;
  const float* W = W1 + (size_t)r * 128 * 128;
  float* C = proj1 + (size_t)r * NN * 128;

  int tx4 = (t & 15) << 2;
  int ty4 = (t >> 4) << 2;
  float acc[4][4] = {};
  int pos = 0;
  for (int k0 = 0; k0 < 128; k0 += 64) {
    if (k0) __syncthreads();
#pragma unroll
    for (int i = 0; i < 4; ++i) {
      int idx = t + i * 256;
      int rr = idx >> 4;
      int c4 = (idx & 15) << 2;
      int grow = row0 + rr;
      float4 v = make_float4(0.f, 0.f, 0.f, 0.f);
      if (grow < NN) v = *(const float4*)(x + (size_t)grow * 128 + k0 + c4);
      *(float4*)(&As[rr][c4]) = v;
    }
#pragma unroll
    for (int i = 0; i < 4; ++i) {
      int idx = t + i * 256;
      int k = idx >> 4;
      int c4 = (idx & 15) << 2;
      *(float4*)(&Bs[k][c4]) = *(const float4*)(W + (size_t)(k0 + k) * 128 + col0 + c4);
    }
    __syncthreads();
    if (k0 == 0 && have) {
      atomicAdd(cnt_out + er * NN + es, 1);       // no return needed
      pos = atomicAdd(cnt_in + er * NN + ed, 1);  // return consumed at kernel end
    }
#pragma unroll 8
    for (int k = 0; k < 64; k += 4) {
      float4 b0 = *(const float4*)(&Bs[k + 0][tx4]);
      float4 b1 = *(const float4*)(&Bs[k + 1][tx4]);
      float4 b2 = *(const float4*)(&Bs[k + 2][tx4]);
      float4 b3 = *(const float4*)(&Bs[k + 3][tx4]);
#pragma unroll
      for (int m = 0; m < 4; ++m) {
        float4 a = *(const float4*)(&As[ty4 + m][k]);
        acc[m][0] += a.x * b0.x + a.y * b1.x + a.z * b2.x + a.w * b3.x;
        acc[m][1] += a.x * b0.y + a.y * b1.y + a.z * b2.y + a.w * b3.y;
        acc[m][2] += a.x * b0.z + a.y * b1.z + a.z * b2.z + a.w * b3.z;
        acc[m][3] += a.x * b0.w + a.y * b1.w + a.z * b2.w + a.w * b3.w;
      }
    }
  }
#pragma unroll
  for (int m = 0; m < 4; ++m) {
    int row = row0 + ty4 + m;
    if (row < NN)
      *(float4*)(C + (size_t)row * 128 + col0 + tx4) =
          make_float4(acc[m][0], acc[m][1], acc[m][2], acc[m][3]);
  }

  // --- consume atomic result ---
  if (have) {
    if (pos < CAP) {
      ell[((size_t)er * NN + ed) * CAP + pos] = (unsigned short)es;
    } else {
      int i = atomicAdd(nspill, 1);
      if (i < MAXSPILL) { spill[3 * i] = er; spill[3 * i + 1] = ed; spill[3 * i + 2] = es; }
    }
  }
}

// standalone GEMMs (fallback path / layer 2)
__global__ __launch_bounds__(256, 3) void gemm1_single_kernel(
    const float* __restrict__ x, const float* __restrict__ W1r, float* __restrict__ proj) {
  gemm_body<false>(x, W1r, nullptr, proj, NN, 128, blockIdx.x * 64, blockIdx.y * 64);
}
__global__ __launch_bounds__(256, 3) void gemm2_kernel(
    const float* __restrict__ h, const float* __restrict__ W2,
    const int* __restrict__ cnt_out, float* __restrict__ proj2, int relStride) {
  int r = blockIdx.z;
  gemm_body<true>(h, W2 + (size_t)r * 128 * 64, cnt_out + r * NN,
                  proj2 + (size_t)r * relStride, NN, 64, blockIdx.x * 64, 0);
}

// fallback build-only kernel
__global__ void ell_build_kernel(const int* __restrict__ edges,
                                 int* __restrict__ cnt_out, int* __restrict__ cnt_in,
                                 unsigned short* __restrict__ ell,
                                 int* __restrict__ nspill, int* __restrict__ spill) {
  int gid = blockIdx.x * blockDim.x + threadIdx.x;
  if (gid >= NREL * NE) return;
  int r = gid / NE;
  int e = gid - r * NE;
  const int* b = edges + (size_t)r * 2 * NE;
  int s = b[e];
  int d = b[NE + e];
  atomicAdd(cnt_out + r * NN + s, 1);
  int pos = atomicAdd(cnt_in + r * NN + d, 1);
  if (pos < CAP) {
    ell[((size_t)r * NN + d) * CAP + pos] = (unsigned short)s;
  } else {
    int i = atomicAdd(nspill, 1);
    if (i < MAXSPILL) { spill[3 * i] = r; spill[3 * i + 1] = d; spill[3 * i + 2] = s; }
  }
}

// ---- layer-1 aggregate, all 3 relations, bias+relu fused; half-wave (32 lanes) per row ----
__global__ __launch_bounds__(256) void agg1_all_kernel(
    const float* __restrict__ proj1, const unsigned short* __restrict__ ell,
    const int* __restrict__ cnt_in, const int* __restrict__ cnt_out,
    const int* __restrict__ nspill, const int* __restrict__ spill,
    const float* __restrict__ b1, float* __restrict__ h) {
  int row = (blockIdx.x * blockDim.x + threadIdx.x) >> 5;
  if (row >= NN) return;
  int lane = threadIdx.x & 31;
  int f = lane * 4;
  float4 q0 = *(const float4*)(b1 + f);
  float4 q1 = *(const float4*)(b1 + 128 + f);
  float4 q2 = *(const float4*)(b1 + 256 + f);
  float4 acc = make_float4(q0.x + q1.x + q2.x, q0.y + q1.y + q2.y,
                           q0.z + q1.z + q2.z, q0.w + q1.w + q2.w);
  int ns = min(*nspill, MAXSPILL);
  for (int r = 0; r < NREL; ++r) {
    const float* P = proj1 + (size_t)r * NN * 128;
    const int* co = cnt_out + r * NN;
    int deg = cnt_in[r * NN + row];
    int n = min(deg, CAP);
    const unsigned short* er = ell + ((size_t)r * NN + row) * CAP;
    float4 a0 = make_float4(0.f, 0.f, 0.f, 0.f);
    float4 a1 = make_float4(0.f, 0.f, 0.f, 0.f);
    int e = 0;
    for (; e + 1 < n; e += 2) {
      int s0 = er[e], s1 = er[e + 1];
      float w0 = rsqrtf((float)max(co[s0], 1));
      float w1 = rsqrtf((float)max(co[s1], 1));
      float4 v0 = *(const float4*)(P + (size_t)s0 * 128 + f);
      float4 v1 = *(const float4*)(P + (size_t)s1 * 128 + f);
      a0.x += w0 * v0.x; a0.y += w0 * v0.y; a0.z += w0 * v0.z; a0.w += w0 * v0.w;
      a1.x += w1 * v1.x; a1.y += w1 * v1.y; a1.z += w1 * v1.z; a1.w += w1 * v1.w;
    }
    if (e < n) {
      int s0 = er[e];
      float w0 = rsqrtf((float)max(co[s0], 1));
      float4 v0 = *(const float4*)(P + (size_t)s0 * 128 + f);
      a0.x += w0 * v0.x; a0.y += w0 * v0.y; a0.z += w0 * v0.z; a0.w += w0 * v0.w;
    }
    for (int i = 0; i < ns; ++i) {
      if (spill[3 * i] == r && spill[3 * i + 1] == row) {
        int s0 = spill[3 * i + 2];
        float w0 = rsqrtf((float)max(co[s0], 1));
        float4 v0 = *(const float4*)(P + (size_t)s0 * 128 + f);
        a0.x += w0 * v0.x; a0.y += w0 * v0.y; a0.z += w0 * v0.z; a0.w += w0 * v0.w;
      }
    }
    float si = rsqrtf((float)max(deg, 1));
    acc.x += (a0.x + a1.x) * si; acc.y += (a0.y + a1.y) * si;
    acc.z += (a0.z + a1.z) * si; acc.w += (a0.w + a1.w) * si;
  }
  acc.x = fmaxf(acc.x, 0.f); acc.y = fmaxf(acc.y, 0.f);
  acc.z = fmaxf(acc.z, 0.f); acc.w = fmaxf(acc.w, 0.f);
  *(float4*)(h + (size_t)row * 128 + f) = acc;
}

// fallback: per-relation L1 aggregate accumulating into h
template <bool FIRST, bool LAST>
__global__ __launch_bounds__(256) void agg1_one_kernel(
    const float* __restrict__ P, const unsigned short* __restrict__ ell_r,
    const int* __restrict__ ci, const int* __restrict__ co,
    const int* __restrict__ nspill, const int* __restrict__ spill,
    int rel, const float* __restrict__ b1, float* __restrict__ h) {
  int row = (blockIdx.x * blockDim.x + threadIdx.x) >> 5;
  if (row >= NN) return;
  int lane = threadIdx.x & 31;
  int f = lane * 4;
  int deg = ci[row];
  int n = min(deg, CAP);
  const unsigned short* er = ell_r + (size_t)row * CAP;
  float4 a0 = make_float4(0.f, 0.f, 0.f, 0.f);
  for (int e = 0; e < n; ++e) {
    int s0 = er[e];
    float w0 = rsqrtf((float)max(co[s0], 1));
    float4 v0 = *(const float4*)(P + (size_t)s0 * 128 + f);
    a0.x += w0 * v0.x; a0.y += w0 * v0.y; a0.z += w0 * v0.z; a0.w += w0 * v0.w;
  }
  int ns = min(*nspill, MAXSPILL);
  for (int i = 0; i < ns; ++i) {
    if (spill[3 * i] == rel && spill[3 * i + 1] == row) {
      int s0 = spill[3 * i + 2];
      float w0 = rsqrtf((float)max(co[s0], 1));
      float4 v0 = *(const float4*)(P + (size_t)s0 * 128 + f);
      a0.x += w0 * v0.x; a0.y += w0 * v0.y; a0.z += w0 * v0.z; a0.w += w0 * v0.w;
    }
  }
  float si = rsqrtf((float)max(deg, 1));
  float4 acc;
  if (FIRST) {
    float4 q0 = *(const float4*)(b1 + f);
    float4 q1 = *(const float4*)(b1 + 128 + f);
    float4 q2 = *(const float4*)(b1 + 256 + f);
    acc = make_float4(q0.x + q1.x + q2.x, q0.y + q1.y + q2.y,
                      q0.z + q1.z + q2.z, q0.w + q1.w + q2.w);
  } else {
    acc = *(const float4*)(h + (size_t)row * 128 + f);
  }
  acc.x += a0.x * si; acc.y += a0.y * si; acc.z += a0.z * si; acc.w += a0.w * si;
  if (LAST) {
    acc.x = fmaxf(acc.x, 0.f); acc.y = fmaxf(acc.y, 0.f);
    acc.z = fmaxf(acc.z, 0.f); acc.w = fmaxf(acc.w, 0.f);
  }
  *(float4*)(h + (size_t)row * 128 + f) = acc;
}

// ---- layer-2 aggregate, all 3 relations, bias fused; quarter-wave (16 lanes) per row ----
__global__ __launch_bounds__(256) void agg2_all_kernel(
    const float* __restrict__ proj2, const unsigned short* __restrict__ ell,
    const int* __restrict__ cnt_in,
    const int* __restrict__ nspill, const int* __restrict__ spill,
    const float* __restrict__ b2, float* __restrict__ out) {
  int row = (blockIdx.x * blockDim.x + threadIdx.x) >> 4;
  if (row >= NN) return;
  int lane = threadIdx.x & 15;
  int f = lane * 4;
  float4 q0 = *(const float4*)(b2 + f);
  float4 q1 = *(const float4*)(b2 + 64 + f);
  float4 q2 = *(const float4*)(b2 + 128 + f);
  float4 acc = make_float4(q0.x + q1.x + q2.x, q0.y + q1.y + q2.y,
                           q0.z + q1.z + q2.z, q0.w + q1.w + q2.w);
  int ns = min(*nspill, MAXSPILL);
  for (int r = 0; r < NREL; ++r) {
    const float* P = proj2 + (size_t)r * NN * 64;
    int deg = cnt_in[r * NN + row];
    int n = min(deg, CAP);
    const unsigned short* er = ell + ((size_t)r * NN + row) * CAP;
    float4 a0 = make_float4(0.f, 0.f, 0.f, 0.f);
    float4 a1 = make_float4(0.f, 0.f, 0.f, 0.f);
    int e = 0;
    for (; e + 1 < n; e += 2) {
      int s0 = er[e], s1 = er[e + 1];
      float4 v0 = *(const float4*)(P + (size_t)s0 * 64 + f);
      float4 v1 = *(const float4*)(P + (size_t)s1 * 64 + f);
      a0.x += v0.x; a0.y += v0.y; a0.z += v0.z; a0.w += v0.w;
      a1.x += v1.x; a1.y += v1.y; a1.z += v1.z; a1.w += v1.w;
    }
    if (e < n) {
      int s0 = er[e];
      float4 v0 = *(const float4*)(P + (size_t)s0 * 64 + f);
      a0.x += v0.x; a0.y += v0.y; a0.z += v0.z; a0.w += v0.w;
    }
    for (int i = 0; i < ns; ++i) {
      if (spill[3 * i] == r && spill[3 * i + 1] == row) {
        int s0 = spill[3 * i + 2];
        float4 v0 = *(const float4*)(P + (size_t)s0 * 64 + f);
        a0.x += v0.x; a0.y += v0.y; a0.z += v0.z; a0.w += v0.w;
      }
    }
    float si = rsqrtf((float)max(deg, 1));
    acc.x += (a0.x + a1.x) * si; acc.y += (a0.y + a1.y) * si;
    acc.z += (a0.z + a1.z) * si; acc.w += (a0.w + a1.w) * si;
  }
  *(float4*)(out + (size_t)row * 64 + f) = acc;
}

// fallback: per-relation L2 aggregate into out
template <bool FIRST>
__global__ __launch_bounds__(256) void agg2_one_kernel(
    const float* __restrict__ P, const unsigned short* __restrict__ ell_r,
    const int* __restrict__ ci,
    const int* __restrict__ nspill, const int* __restrict__ spill,
    int rel, const float* __restrict__ b2, float* __restrict__ out) {
  int row = (blockIdx.x * blockDim.x + threadIdx.x) >> 4;
  if (row >= NN) return;
  int lane = threadIdx.x & 15;
  int f = lane * 4;
  int deg = ci[row];
  int n = min(deg, CAP);
  const unsigned short* er = ell_r + (size_t)row * CAP;
  float4 a0 = make_float4(0.f, 0.f, 0.f, 0.f);
  for (int e = 0; e < n; ++e) {
    int s0 = er[e];
    float4 v0 = *(const float4*)(P + (size_t)s0 * 64 + f);
    a0.x += v0.x; a0.y += v0.y; a0.z += v0.z; a0.w += v0.w;
  }
  int ns = min(*nspill, MAXSPILL);
  for (int i = 0; i < ns; ++i) {
    if (spill[3 * i] == rel && spill[3 * i + 1] == row) {
      int s0 = spill[3 * i + 2];
      float4 v0 = *(const float4*)(P + (size_t)s0 * 64 + f);
      a0.x += v0.x; a0.y += v0.y; a0.z += v0.z; a0.w += v0.w;
    }
  }
  float si = rsqrtf((float)max(deg, 1));
  float4 acc;
  if (FIRST) {
    float4 q0 = *(const float4*)(b2 + f);
    float4 q1 = *(const float4*)(b2 + 64 + f);
    float4 q2 = *(const float4*)(b2 + 128 + f);
    acc = make_float4(q0.x + q1.x + q2.x, q0.y + q1.y + q2.y,
                      q0.z + q1.z + q2.z, q0.w + q1.w + q2.w);
  } else {
    acc = *(const float4*)(out + (size_t)row * 64 + f);
  }
  acc.x += a0.x * si; acc.y += a0.y * si; acc.z += a0.z * si; acc.w += a0.w * si;
  *(float4*)(out + (size_t)row * 64 + f) = acc;
}

extern "C" void kernel_launch(void* const* d_in, const int* in_sizes, int n_in,
                              void* d_out, int out_size, void* d_ws, size_t ws_size,
                              hipStream_t stream) {
  const float* x   = (const float*)d_in[0];
  const int* edges = (const int*)d_in[1];
  const float* W1  = (const float*)d_in[2];
  const float* b1  = (const float*)d_in[3];
  const float* W2  = (const float*)d_in[4];
  const float* b2  = (const float*)d_in[5];
  float* out = (float*)d_out;
  char* wsb = (char*)d_ws;

  const size_t PROJ1_FULL = (size_t)NREL * NN * 128 * 4;  // 76.8 MB
  const size_t PROJ1_ONE  = (size_t)NN * 128 * 4;         // 25.6 MB
  const size_t H_BYTES    = (size_t)NN * 128 * 4;         // 25.6 MB
  const size_t ELL_BYTES  = (size_t)NREL * NN * CAP * 2;  // 7.2 MB
  const size_t CNT_BYTES  = (size_t)NREL * NN * 4;        // 0.6 MB
  const size_t FULL_NEED = PROJ1_FULL + H_BYTES + ELL_BYTES + 2 * CNT_BYTES + 16 + 3 * MAXSPILL * 4;
  bool full = ws_size >= FULL_NEED;

  size_t projBytes = full ? PROJ1_FULL : PROJ1_ONE;
  float* proj = (float*)wsb;                               // proj1 (and proj2 reuse)
  float* h    = (float*)(wsb + projBytes);
  unsigned short* ell = (unsigned short*)(wsb + projBytes + H_BYTES);
  int* cnt_out = (int*)(wsb + projBytes + H_BYTES + ELL_BYTES);
  int* cnt_in  = cnt_out + NREL * NN;
  int* nspill  = cnt_in + NREL * NN;
  int* spill   = nspill + 4;

  // zero counters + spill count
  hipMemsetAsync(cnt_out, 0, 2 * CNT_BYTES + 16, stream);

  const int agg1Blocks = (NN * 32 + 255) / 256;
  const int agg2Blocks = (NN * 16 + 255) / 256;

  if (full) {
    fused_build_gemm1_kernel<<<GEMM1_BLKS, 256, 0, stream>>>(
        edges, cnt_out, cnt_in, ell, nspill, spill, x, W1, proj);
    agg1_all_kernel<<<agg1Blocks, 256, 0, stream>>>(
        proj, ell, cnt_in, cnt_out, nspill, spill, b1, h);
    gemm2_kernel<<<dim3(G1X, 1, NREL), 256, 0, stream>>>(h, W2, cnt_out, proj, NN * 64);
    agg2_all_kernel<<<agg2Blocks, 256, 0, stream>>>(
        proj, ell, cnt_in, nspill, spill, b2, out);
  } else {
    ell_build_kernel<<<(NREL * NE + 255) / 256, 256, 0, stream>>>(
        edges, cnt_out, cnt_in, ell, nspill, spill);
    for (int r = 0; r < NREL; ++r) {
      gemm1_single_kernel<<<dim3(G1X, 2), 256, 0, stream>>>(
          x, W1 + (size_t)r * 128 * 128, proj);
      unsigned short* ell_r = ell + (size_t)r * NN * CAP;
      if (r == 0)
        agg1_one_kernel<true, false><<<agg1Blocks, 256, 0, stream>>>(
            proj, ell_r, cnt_in + r * NN, cnt_out + r * NN, nspill, spill, r, b1, h);
      else if (r == 1)
        agg1_one_kernel<false, false><<<agg1Blocks, 256, 0, stream>>>(
            proj, ell_r, cnt_in + r * NN, cnt_out + r * NN, nspill, spill, r, b1, h);
      else
        agg1_one_kernel<false, true><<<agg1Blocks, 256, 0, stream>>>(
            proj, ell_r, cnt_in + r * NN, cnt_out + r * NN, nspill, spill, r, b1, h);
    }
    for (int r = 0; r < NREL; ++r) {
      gemm2_kernel<<<dim3(G1X, 1, 1), 256, 0, stream>>>(
          h, W2 + (size_t)r * 128 * 64, cnt_out + r * NN, proj, 0);
      unsigned short* ell_r = ell + (size_t)r * NN * CAP;
      if (r == 0)
        agg2_one_kernel<true><<<agg2Blocks, 256, 0, stream>>>(
            proj, ell_r, cnt_in + r * NN, nspill, spill, r, b2, out);
      else
        agg2_one_kernel<false><<<agg2Blocks, 256, 0, stream>>>(
            proj, ell_r, cnt_in + r * NN, nspill, spill, r, b2, out);
    }
  }
}

// Round 7
// 268.890 us; speedup vs baseline: 4.2291x; 1.1557x over previous
//
#include <hip/hip_runtime.h>

constexpr int NN = 50000;
constexpr int NREL = 3;
constexpr int NE = 400000;
constexpr int CAP = 24;        // ELL capacity; Poisson(8) tail at 24 ~ 4e-9/node
constexpr int MAXSPILL = 4096;

constexpr int G1X = (NN + 63) / 64;           // 782 row-tiles
constexpr int GEMM1_BLKS = G1X * 2 * NREL;    // 4692 blocks; >= 4688 edge chunks
constexpr int LDA = 68;                       // BK=64 + 4 pad

// ---- bf16 <-> f32 bit helpers (finite inputs; RNE on store) ----
__device__ __forceinline__ float b2f(unsigned short u) {
  union { unsigned int i; float f; } v; v.i = (unsigned int)u << 16; return v.f;
}
__device__ __forceinline__ unsigned short f2b(float f) {
  union { float f; unsigned int i; } v; v.f = f;
  unsigned int r = v.i + 0x7fffu + ((v.i >> 16) & 1u);
  return (unsigned short)(r >> 16);
}

// ---- GEMM tile body, BK=64 two-stage: C_bf16[M][N] = (A * rsqrt(cnt)?) @ W_f32 ----
// A is fp32 (INBF=false) or bf16-as-ushort (INBF=true). LDS 33.8 KB -> 3 blocks/CU.
template <bool SCALE, bool INBF>
__device__ __forceinline__ void gemm_body(
    const void* __restrict__ Av, const float* __restrict__ W,
    const int* __restrict__ cnt_scale, unsigned short* __restrict__ C,
    int M, int N, int row0, int col0) {
  __shared__ float As[64][LDA];
  __shared__ float Bs[64][64];
  int t = threadIdx.x;
  int tx4 = (t & 15) << 2;
  int ty4 = (t >> 4) << 2;
  float acc[4][4] = {};
  for (int k0 = 0; k0 < 128; k0 += 64) {
    if (k0) __syncthreads();
#pragma unroll
    for (int i = 0; i < 4; ++i) {
      int idx = t + i * 256;             // 1024 float4 slots
      int r = idx >> 4;
      int c4 = (idx & 15) << 2;
      int grow = row0 + r;
      float4 v = make_float4(0.f, 0.f, 0.f, 0.f);
      if (grow < M) {
        if (INBF) {
          ushort4 u = *(const ushort4*)((const unsigned short*)Av + (size_t)grow * 128 + k0 + c4);
          v = make_float4(b2f(u.x), b2f(u.y), b2f(u.z), b2f(u.w));
        } else {
          v = *(const float4*)((const float*)Av + (size_t)grow * 128 + k0 + c4);
        }
        if (SCALE) {
          float s = rsqrtf((float)max(cnt_scale[grow], 1));
          v.x *= s; v.y *= s; v.z *= s; v.w *= s;
        }
      }
      *(float4*)(&As[r][c4]) = v;
    }
#pragma unroll
    for (int i = 0; i < 4; ++i) {
      int idx = t + i * 256;
      int k = idx >> 4;
      int c4 = (idx & 15) << 2;
      *(float4*)(&Bs[k][c4]) = *(const float4*)(W + (size_t)(k0 + k) * N + col0 + c4);
    }
    __syncthreads();
#pragma unroll 8
    for (int k = 0; k < 64; k += 4) {
      float4 b0 = *(const float4*)(&Bs[k + 0][tx4]);
      float4 b1 = *(const float4*)(&Bs[k + 1][tx4]);
      float4 b2 = *(const float4*)(&Bs[k + 2][tx4]);
      float4 b3 = *(const float4*)(&Bs[k + 3][tx4]);
#pragma unroll
      for (int m = 0; m < 4; ++m) {
        float4 a = *(const float4*)(&As[ty4 + m][k]);
        acc[m][0] += a.x * b0.x + a.y * b1.x + a.z * b2.x + a.w * b3.x;
        acc[m][1] += a.x * b0.y + a.y * b1.y + a.z * b2.y + a.w * b3.y;
        acc[m][2] += a.x * b0.z + a.y * b1.z + a.z * b2.z + a.w * b3.z;
        acc[m][3] += a.x * b0.w + a.y * b1.w + a.z * b2.w + a.w * b3.w;
      }
    }
  }
#pragma unroll
  for (int m = 0; m < 4; ++m) {
    int row = row0 + ty4 + m;
    if (row < M) {
      ushort4 o;
      o.x = f2b(acc[m][0]); o.y = f2b(acc[m][1]);
      o.z = f2b(acc[m][2]); o.w = f2b(acc[m][3]);
      *(ushort4*)(C + (size_t)row * N + col0 + tx4) = o;
    }
  }
}

// ---- fused: every block = 1 GEMM tile of proj1_r = x@W1_r (bf16 out) + 256 edges of ELL build.
__global__ __launch_bounds__(256, 3) void fused_build_gemm1_kernel(
    const int* __restrict__ edges, int* __restrict__ cnt_out, int* __restrict__ cnt_in,
    unsigned short* __restrict__ ell, int* __restrict__ nspill, int* __restrict__ spill,
    const float* __restrict__ x, const float* __restrict__ W1, unsigned short* __restrict__ proj1) {
  __shared__ float As[64][LDA];
  __shared__ float Bs[64][64];
  int t = threadIdx.x;

  // --- edge slice ---
  int eg = blockIdx.x * 256 + t;
  bool have = (eg < NREL * NE);
  int er = 0, es = 0, ed = 0;
  if (have) {
    er = eg / NE;
    int e = eg - er * NE;
    const int* b = edges + (size_t)er * 2 * NE;
    es = b[e];
    ed = b[NE + e];
  }

  // --- GEMM tile mapping ---
  int g = blockIdx.x;
  int r = g / (G1X * 2);
  int rem = g - r * (G1X * 2);
  int row0 = (rem >> 1) * 64;
  int col0 = (rem & 1) * 64;
  const float* W = W1 + (size_t)r * 128 * 128;
  unsigned short* C = proj1 + (size_t)r * NN * 128;

  int tx4 = (t & 15) << 2;
  int ty4 = (t >> 4) << 2;
  float acc[4][4] = {};
  int pos = 0;
  for (int k0 = 0; k0 < 128; k0 += 64) {
    if (k0) __syncthreads();
#pragma unroll
    for (int i = 0; i < 4; ++i) {
      int idx = t + i * 256;
      int rr = idx >> 4;
      int c4 = (idx & 15) << 2;
      int grow = row0 + rr;
      float4 v = make_float4(0.f, 0.f, 0.f, 0.f);
      if (grow < NN) v = *(const float4*)(x + (size_t)grow * 128 + k0 + c4);
      *(float4*)(&As[rr][c4]) = v;
    }
#pragma unroll
    for (int i = 0; i < 4; ++i) {
      int idx = t + i * 256;
      int k = idx >> 4;
      int c4 = (idx & 15) << 2;
      *(float4*)(&Bs[k][c4]) = *(const float4*)(W + (size_t)(k0 + k) * 128 + col0 + c4);
    }
    __syncthreads();
    if (k0 == 0 && have) {
      atomicAdd(cnt_out + er * NN + es, 1);       // no return needed
      pos = atomicAdd(cnt_in + er * NN + ed, 1);  // return consumed at kernel end
    }
#pragma unroll 8
    for (int k = 0; k < 64; k += 4) {
      float4 b0 = *(const float4*)(&Bs[k + 0][tx4]);
      float4 b1 = *(const float4*)(&Bs[k + 1][tx4]);
      float4 b2 = *(const float4*)(&Bs[k + 2][tx4]);
      float4 b3 = *(const float4*)(&Bs[k + 3][tx4]);
#pragma unroll
      for (int m = 0; m < 4; ++m) {
        float4 a = *(const float4*)(&As[ty4 + m][k]);
        acc[m][0] += a.x * b0.x + a.y * b1.x + a.z * b2.x + a.w * b3.x;
        acc[m][1] += a.x * b0.y + a.y * b1.y + a.z * b2.y + a.w * b3.y;
        acc[m][2] += a.x * b0.z + a.y * b1.z + a.z * b2.z + a.w * b3.z;
        acc[m][3] += a.x * b0.w + a.y * b1.w + a.z * b2.w + a.w * b3.w;
      }
    }
  }
#pragma unroll
  for (int m = 0; m < 4; ++m) {
    int row = row0 + ty4 + m;
    if (row < NN) {
      ushort4 o;
      o.x = f2b(acc[m][0]); o.y = f2b(acc[m][1]);
      o.z = f2b(acc[m][2]); o.w = f2b(acc[m][3]);
      *(ushort4*)(C + (size_t)row * 128 + col0 + tx4) = o;
    }
  }

  // --- consume atomic result ---
  if (have) {
    if (pos < CAP) {
      ell[((size_t)er * NN + ed) * CAP + pos] = (unsigned short)es;
    } else {
      int i = atomicAdd(nspill, 1);
      if (i < MAXSPILL) { spill[3 * i] = er; spill[3 * i + 1] = ed; spill[3 * i + 2] = es; }
    }
  }
}

// standalone GEMMs (fallback path / layer 2)
__global__ __launch_bounds__(256, 3) void gemm1_single_kernel(
    const float* __restrict__ x, const float* __restrict__ W1r, unsigned short* __restrict__ proj) {
  gemm_body<false, false>(x, W1r, nullptr, proj, NN, 128, blockIdx.x * 64, blockIdx.y * 64);
}
__global__ __launch_bounds__(256, 3) void gemm2_kernel(
    const unsigned short* __restrict__ h, const float* __restrict__ W2,
    const int* __restrict__ cnt_out, unsigned short* __restrict__ proj2, int relStride) {
  int r = blockIdx.z;
  gemm_body<true, true>(h, W2 + (size_t)r * 128 * 64, cnt_out + r * NN,
                        proj2 + (size_t)r * relStride, NN, 64, blockIdx.x * 64, 0);
}

// fallback build-only kernel
__global__ void ell_build_kernel(const int* __restrict__ edges,
                                 int* __restrict__ cnt_out, int* __restrict__ cnt_in,
                                 unsigned short* __restrict__ ell,
                                 int* __restrict__ nspill, int* __restrict__ spill) {
  int gid = blockIdx.x * blockDim.x + threadIdx.x;
  if (gid >= NREL * NE) return;
  int r = gid / NE;
  int e = gid - r * NE;
  const int* b = edges + (size_t)r * 2 * NE;
  int s = b[e];
  int d = b[NE + e];
  atomicAdd(cnt_out + r * NN + s, 1);
  int pos = atomicAdd(cnt_in + r * NN + d, 1);
  if (pos < CAP) {
    ell[((size_t)r * NN + d) * CAP + pos] = (unsigned short)s;
  } else {
    int i = atomicAdd(nspill, 1);
    if (i < MAXSPILL) { spill[3 * i] = r; spill[3 * i + 1] = d; spill[3 * i + 2] = s; }
  }
}

// ---- layer-1 aggregate, all 3 relations, bias+relu fused; half-wave per row; bf16 in/out ----
__global__ __launch_bounds__(256) void agg1_all_kernel(
    const unsigned short* __restrict__ proj1, const unsigned short* __restrict__ ell,
    const int* __restrict__ cnt_in, const int* __restrict__ cnt_out,
    const int* __restrict__ nspill, const int* __restrict__ spill,
    const float* __restrict__ b1, unsigned short* __restrict__ h) {
  int row = (blockIdx.x * blockDim.x + threadIdx.x) >> 5;
  if (row >= NN) return;
  int lane = threadIdx.x & 31;
  int f = lane * 4;
  float4 q0 = *(const float4*)(b1 + f);
  float4 q1 = *(const float4*)(b1 + 128 + f);
  float4 q2 = *(const float4*)(b1 + 256 + f);
  float4 acc = make_float4(q0.x + q1.x + q2.x, q0.y + q1.y + q2.y,
                           q0.z + q1.z + q2.z, q0.w + q1.w + q2.w);
  int ns = min(*nspill, MAXSPILL);
  for (int r = 0; r < NREL; ++r) {
    const unsigned short* P = proj1 + (size_t)r * NN * 128;
    const int* co = cnt_out + r * NN;
    int deg = cnt_in[r * NN + row];
    int n = min(deg, CAP);
    const unsigned short* er = ell + ((size_t)r * NN + row) * CAP;
    float4 a0 = make_float4(0.f, 0.f, 0.f, 0.f);
    float4 a1 = make_float4(0.f, 0.f, 0.f, 0.f);
    int e = 0;
    for (; e + 1 < n; e += 2) {
      int s0 = er[e], s1 = er[e + 1];
      float w0 = rsqrtf((float)max(co[s0], 1));
      float w1 = rsqrtf((float)max(co[s1], 1));
      ushort4 u0 = *(const ushort4*)(P + (size_t)s0 * 128 + f);
      ushort4 u1 = *(const ushort4*)(P + (size_t)s1 * 128 + f);
      a0.x += w0 * b2f(u0.x); a0.y += w0 * b2f(u0.y); a0.z += w0 * b2f(u0.z); a0.w += w0 * b2f(u0.w);
      a1.x += w1 * b2f(u1.x); a1.y += w1 * b2f(u1.y); a1.z += w1 * b2f(u1.z); a1.w += w1 * b2f(u1.w);
    }
    if (e < n) {
      int s0 = er[e];
      float w0 = rsqrtf((float)max(co[s0], 1));
      ushort4 u0 = *(const ushort4*)(P + (size_t)s0 * 128 + f);
      a0.x += w0 * b2f(u0.x); a0.y += w0 * b2f(u0.y); a0.z += w0 * b2f(u0.z); a0.w += w0 * b2f(u0.w);
    }
    for (int i = 0; i < ns; ++i) {
      if (spill[3 * i] == r && spill[3 * i + 1] == row) {
        int s0 = spill[3 * i + 2];
        float w0 = rsqrtf((float)max(co[s0], 1));
        ushort4 u0 = *(const ushort4*)(P + (size_t)s0 * 128 + f);
        a0.x += w0 * b2f(u0.x); a0.y += w0 * b2f(u0.y); a0.z += w0 * b2f(u0.z); a0.w += w0 * b2f(u0.w);
      }
    }
    float si = rsqrtf((float)max(deg, 1));
    acc.x += (a0.x + a1.x) * si; acc.y += (a0.y + a1.y) * si;
    acc.z += (a0.z + a1.z) * si; acc.w += (a0.w + a1.w) * si;
  }
  ushort4 o;
  o.x = f2b(fmaxf(acc.x, 0.f)); o.y = f2b(fmaxf(acc.y, 0.f));
  o.z = f2b(fmaxf(acc.z, 0.f)); o.w = f2b(fmaxf(acc.w, 0.f));
  *(ushort4*)(h + (size_t)row * 128 + f) = o;
}

// fallback: per-relation L1 aggregate accumulating into bf16 h
template <bool FIRST, bool LAST>
__global__ __launch_bounds__(256) void agg1_one_kernel(
    const unsigned short* __restrict__ P, const unsigned short* __restrict__ ell_r,
    const int* __restrict__ ci, const int* __restrict__ co,
    const int* __restrict__ nspill, const int* __restrict__ spill,
    int rel, const float* __restrict__ b1, unsigned short* __restrict__ h) {
  int row = (blockIdx.x * blockDim.x + threadIdx.x) >> 5;
  if (row >= NN) return;
  int lane = threadIdx.x & 31;
  int f = lane * 4;
  int deg = ci[row];
  int n = min(deg, CAP);
  const unsigned short* er = ell_r + (size_t)row * CAP;
  float4 a0 = make_float4(0.f, 0.f, 0.f, 0.f);
  for (int e = 0; e < n; ++e) {
    int s0 = er[e];
    float w0 = rsqrtf((float)max(co[s0], 1));
    ushort4 u0 = *(const ushort4*)(P + (size_t)s0 * 128 + f);
    a0.x += w0 * b2f(u0.x); a0.y += w0 * b2f(u0.y); a0.z += w0 * b2f(u0.z); a0.w += w0 * b2f(u0.w);
  }
  int ns = min(*nspill, MAXSPILL);
  for (int i = 0; i < ns; ++i) {
    if (spill[3 * i] == rel && spill[3 * i + 1] == row) {
      int s0 = spill[3 * i + 2];
      float w0 = rsqrtf((float)max(co[s0], 1));
      ushort4 u0 = *(const ushort4*)(P + (size_t)s0 * 128 + f);
      a0.x += w0 * b2f(u0.x); a0.y += w0 * b2f(u0.y); a0.z += w0 * b2f(u0.z); a0.w += w0 * b2f(u0.w);
    }
  }
  float si = rsqrtf((float)max(deg, 1));
  float4 acc;
  if (FIRST) {
    float4 q0 = *(const float4*)(b1 + f);
    float4 q1 = *(const float4*)(b1 + 128 + f);
    float4 q2 = *(const float4*)(b1 + 256 + f);
    acc = make_float4(q0.x + q1.x + q2.x, q0.y + q1.y + q2.y,
                      q0.z + q1.z + q2.z, q0.w + q1.w + q2.w);
  } else {
    ushort4 u = *(const ushort4*)(h + (size_t)row * 128 + f);
    acc = make_float4(b2f(u.x), b2f(u.y), b2f(u.z), b2f(u.w));
  }
  acc.x += a0.x * si; acc.y += a0.y * si; acc.z += a0.z * si; acc.w += a0.w * si;
  if (LAST) {
    acc.x = fmaxf(acc.x, 0.f); acc.y = fmaxf(acc.y, 0.f);
    acc.z = fmaxf(acc.z, 0.f); acc.w = fmaxf(acc.w, 0.f);
  }
  ushort4 o;
  o.x = f2b(acc.x); o.y = f2b(acc.y); o.z = f2b(acc.z); o.w = f2b(acc.w);
  *(ushort4*)(h + (size_t)row * 128 + f) = o;
}

// ---- layer-2 aggregate, all 3 relations, bias fused; quarter-wave per row; bf16 in, f32 out ----
__global__ __launch_bounds__(256) void agg2_all_kernel(
    const unsigned short* __restrict__ proj2, const unsigned short* __restrict__ ell,
    const int* __restrict__ cnt_in,
    const int* __restrict__ nspill, const int* __restrict__ spill,
    const float* __restrict__ b2, float* __restrict__ out) {
  int row = (blockIdx.x * blockDim.x + threadIdx.x) >> 4;
  if (row >= NN) return;
  int lane = threadIdx.x & 15;
  int f = lane * 4;
  float4 q0 = *(const float4*)(b2 + f);
  float4 q1 = *(const float4*)(b2 + 64 + f);
  float4 q2 = *(const float4*)(b2 + 128 + f);
  float4 acc = make_float4(q0.x + q1.x + q2.x, q0.y + q1.y + q2.y,
                           q0.z + q1.z + q2.z, q0.w + q1.w + q2.w);
  int ns = min(*nspill, MAXSPILL);
  for (int r = 0; r < NREL; ++r) {
    const unsigned short* P = proj2 + (size_t)r * NN * 64;
    int deg = cnt_in[r * NN + row];
    int n = min(deg, CAP);
    const unsigned short* er = ell + ((size_t)r * NN + row) * CAP;
    float4 a0 = make_float4(0.f, 0.f, 0.f, 0.f);
    float4 a1 = make_float4(0.f, 0.f, 0.f, 0.f);
    int e = 0;
    for (; e + 1 < n; e += 2) {
      int s0 = er[e], s1 = er[e + 1];
      ushort4 u0 = *(const ushort4*)(P + (size_t)s0 * 64 + f);
      ushort4 u1 = *(const ushort4*)(P + (size_t)s1 * 64 + f);
      a0.x += b2f(u0.x); a0.y += b2f(u0.y); a0.z += b2f(u0.z); a0.w += b2f(u0.w);
      a1.x += b2f(u1.x); a1.y += b2f(u1.y); a1.z += b2f(u1.z); a1.w += b2f(u1.w);
    }
    if (e < n) {
      int s0 = er[e];
      ushort4 u0 = *(const ushort4*)(P + (size_t)s0 * 64 + f);
      a0.x += b2f(u0.x); a0.y += b2f(u0.y); a0.z += b2f(u0.z); a0.w += b2f(u0.w);
    }
    for (int i = 0; i < ns; ++i) {
      if (spill[3 * i] == r && spill[3 * i + 1] == row) {
        int s0 = spill[3 * i + 2];
        ushort4 u0 = *(const ushort4*)(P + (size_t)s0 * 64 + f);
        a0.x += b2f(u0.x); a0.y += b2f(u0.y); a0.z += b2f(u0.z); a0.w += b2f(u0.w);
      }
    }
    float si = rsqrtf((float)max(deg, 1));
    acc.x += (a0.x + a1.x) * si; acc.y += (a0.y + a1.y) * si;
    acc.z += (a0.z + a1.z) * si; acc.w += (a0.w + a1.w) * si;
  }
  *(float4*)(out + (size_t)row * 64 + f) = acc;
}

// fallback: per-relation L2 aggregate into out
template <bool FIRST>
__global__ __launch_bounds__(256) void agg2_one_kernel(
    const unsigned short* __restrict__ P, const unsigned short* __restrict__ ell_r,
    const int* __restrict__ ci,
    const int* __restrict__ nspill, const int* __restrict__ spill,
    int rel, const float* __restrict__ b2, float* __restrict__ out) {
  int row = (blockIdx.x * blockDim.x + threadIdx.x) >> 4;
  if (row >= NN) return;
  int lane = threadIdx.x & 15;
  int f = lane * 4;
  int deg = ci[row];
  int n = min(deg, CAP);
  const unsigned short* er = ell_r + (size_t)row * CAP;
  float4 a0 = make_float4(0.f, 0.f, 0.f, 0.f);
  for (int e = 0; e < n; ++e) {
    int s0 = er[e];
    ushort4 u0 = *(const ushort4*)(P + (size_t)s0 * 64 + f);
    a0.x += b2f(u0.x); a0.y += b2f(u0.y); a0.z += b2f(u0.z); a0.w += b2f(u0.w);
  }
  int ns = min(*nspill, MAXSPILL);
  for (int i = 0; i < ns; ++i) {
    if (spill[3 * i] == rel && spill[3 * i + 1] == row) {
      int s0 = spill[3 * i + 2];
      ushort4 u0 = *(const ushort4*)(P + (size_t)s0 * 64 + f);
      a0.x += b2f(u0.x); a0.y += b2f(u0.y); a0.z += b2f(u0.z); a0.w += b2f(u0.w);
    }
  }
  float si = rsqrtf((float)max(deg, 1));
  float4 acc;
  if (FIRST) {
    float4 q0 = *(const float4*)(b2 + f);
    float4 q1 = *(const float4*)(b2 + 64 + f);
    float4 q2 = *(const float4*)(b2 + 128 + f);
    acc = make_float4(q0.x + q1.x + q2.x, q0.y + q1.y + q2.y,
                      q0.z + q1.z + q2.z, q0.w + q1.w + q2.w);
  } else {
    acc = *(const float4*)(out + (size_t)row * 64 + f);
  }
  acc.x += a0.x * si; acc.y += a0.y * si; acc.z += a0.z * si; acc.w += a0.w * si;
  *(float4*)(out + (size_t)row * 64 + f) = acc;
}

extern "C" void kernel_launch(void* const* d_in, const int* in_sizes, int n_in,
                              void* d_out, int out_size, void* d_ws, size_t ws_size,
                              hipStream_t stream) {
  const float* x   = (const float*)d_in[0];
  const int* edges = (const int*)d_in[1];
  const float* W1  = (const float*)d_in[2];
  const float* b1  = (const float*)d_in[3];
  const float* W2  = (const float*)d_in[4];
  const float* b2  = (const float*)d_in[5];
  float* out = (float*)d_out;
  char* wsb = (char*)d_ws;

  const size_t PROJ_FULL = (size_t)NREL * NN * 128 * 2;  // 38.4 MB bf16
  const size_t PROJ_ONE  = (size_t)NN * 128 * 2;         // 12.8 MB
  const size_t H_BYTES   = (size_t)NN * 128 * 2;         // 12.8 MB bf16
  const size_t ELL_BYTES = (size_t)NREL * NN * CAP * 2;  // 7.2 MB
  const size_t CNT_BYTES = (size_t)NREL * NN * 4;        // 0.6 MB
  const size_t FULL_NEED = PROJ_FULL + H_BYTES + ELL_BYTES + 2 * CNT_BYTES + 16 + 3 * MAXSPILL * 4;
  bool full = ws_size >= FULL_NEED;

  size_t projBytes = full ? PROJ_FULL : PROJ_ONE;
  unsigned short* proj = (unsigned short*)wsb;             // proj1 (and proj2 reuse)
  unsigned short* h    = (unsigned short*)(wsb + projBytes);
  unsigned short* ell  = (unsigned short*)(wsb + projBytes + H_BYTES);
  int* cnt_out = (int*)(wsb + projBytes + H_BYTES + ELL_BYTES);
  int* cnt_in  = cnt_out + NREL * NN;
  int* nspill  = cnt_in + NREL * NN;
  int* spill   = nspill + 4;

  // zero counters + spill count
  hipMemsetAsync(cnt_out, 0, 2 * CNT_BYTES + 16, stream);

  const int agg1Blocks = (NN * 32 + 255) / 256;
  const int agg2Blocks = (NN * 16 + 255) / 256;

  if (full) {
    fused_build_gemm1_kernel<<<GEMM1_BLKS, 256, 0, stream>>>(
        edges, cnt_out, cnt_in, ell, nspill, spill, x, W1, proj);
    agg1_all_kernel<<<agg1Blocks, 256, 0, stream>>>(
        proj, ell, cnt_in, cnt_out, nspill, spill, b1, h);
    gemm2_kernel<<<dim3(G1X, 1, NREL), 256, 0, stream>>>(h, W2, cnt_out, proj, NN * 64);
    agg2_all_kernel<<<agg2Blocks, 256, 0, stream>>>(
        proj, ell, cnt_in, nspill, spill, b2, out);
  } else {
    ell_build_kernel<<<(NREL * NE + 255) / 256, 256, 0, stream>>>(
        edges, cnt_out, cnt_in, ell, nspill, spill);
    for (int r = 0; r < NREL; ++r) {
      gemm1_single_kernel<<<dim3(G1X, 2), 256, 0, stream>>>(
          x, W1 + (size_t)r * 128 * 128, proj);
      unsigned short* ell_r = ell + (size_t)r * NN * CAP;
      if (r == 0)
        agg1_one_kernel<true, false><<<agg1Blocks, 256, 0, stream>>>(
            proj, ell_r, cnt_in + r * NN, cnt_out + r * NN, nspill, spill, r, b1, h);
      else if (r == 1)
        agg1_one_kernel<false, false><<<agg1Blocks, 256, 0, stream>>>(
            proj, ell_r, cnt_in + r * NN, cnt_out + r * NN, nspill, spill, r, b1, h);
      else
        agg1_one_kernel<false, true><<<agg1Blocks, 256, 0, stream>>>(
            proj, ell_r, cnt_in + r * NN, cnt_out + r * NN, nspill, spill, r, b1, h);
    }
    for (int r = 0; r < NREL; ++r) {
      gemm2_kernel<<<dim3(G1X, 1, 1), 256, 0, stream>>>(
          h, W2 + (size_t)r * 128 * 64, cnt_out + r * NN, proj, 0);
      unsigned short* ell_r = ell + (size_t)r * NN * CAP;
      if (r == 0)
        agg2_one_kernel<true><<<agg2Blocks, 256, 0, stream>>>(
            proj, ell_r, cnt_in + r * NN, nspill, spill, r, b2, out);
      else
        agg2_one_kernel<false><<<agg2Blocks, 256, 0, stream>>>(
            proj, ell_r, cnt_in + r * NN, nspill, spill, r, b2, out);
    }
  }
}